// Round 1
// baseline (743.413 us; speedup 1.0000x reference)
//
#include <hip/hip_runtime.h>
#include <hip/hip_bf16.h>
#include <math.h>

// Problem constants
#define BB 4
#define NN 1024
#define DD 256
#define CC 8
#define KNBR 16
#define MAXSEL 17   // 16 top-k + possibly the diagonal

// ---------------------------------------------------------------------------
// Kernel 1: qk = x @ W  ([4096,256] @ [256,4096]), scatter into q,k [B,C,N,D]
// fp32 tiled GEMM: 128x128 tile, BK=16, 256 threads, 8x8 per thread.
// ---------------------------------------------------------------------------
__global__ __launch_bounds__(256) void gemm_xw(const float* __restrict__ A,
                                               const float* __restrict__ Bw,
                                               float* __restrict__ q,
                                               float* __restrict__ kbuf) {
    const int K = 256, Nc = 4096;
    __shared__ float As[16][132];   // [k][row], pad 4 keeps float4 alignment
    __shared__ float Bs[16][132];   // [k][col]
    const int tid = threadIdx.x;
    const int tx = tid & 15, ty = tid >> 4;
    const int row0 = blockIdx.y * 128, col0 = blockIdx.x * 128;

    float acc[8][8];
#pragma unroll
    for (int i = 0; i < 8; i++)
#pragma unroll
        for (int j = 0; j < 8; j++) acc[i][j] = 0.f;

    for (int k0 = 0; k0 < K; k0 += 16) {
        {   // A tile: 128 rows x 16 k
            int r = tid >> 1;
            int kk = (tid & 1) * 8;
            const float* src = A + (size_t)(row0 + r) * K + k0 + kk;
            float4 v0 = *(const float4*)(src);
            float4 v1 = *(const float4*)(src + 4);
            As[kk + 0][r] = v0.x; As[kk + 1][r] = v0.y;
            As[kk + 2][r] = v0.z; As[kk + 3][r] = v0.w;
            As[kk + 4][r] = v1.x; As[kk + 5][r] = v1.y;
            As[kk + 6][r] = v1.z; As[kk + 7][r] = v1.w;
        }
        {   // B tile: 16 k x 128 cols (row-major, coalesced)
            int r = tid >> 4;
            int cb = (tid & 15) * 8;
            const float* src = Bw + (size_t)(k0 + r) * Nc + col0 + cb;
            float4 v0 = *(const float4*)(src);
            float4 v1 = *(const float4*)(src + 4);
            *(float4*)&Bs[r][cb] = v0;
            *(float4*)&Bs[r][cb + 4] = v1;
        }
        __syncthreads();
#pragma unroll
        for (int kk = 0; kk < 16; kk++) {
            float a[8], b[8];
            *(float4*)&a[0] = *(float4*)&As[kk][ty * 8];
            *(float4*)&a[4] = *(float4*)&As[kk][ty * 8 + 4];
            *(float4*)&b[0] = *(float4*)&Bs[kk][tx * 8];
            *(float4*)&b[4] = *(float4*)&Bs[kk][tx * 8 + 4];
#pragma unroll
            for (int i = 0; i < 8; i++)
#pragma unroll
                for (int j = 0; j < 8; j++) acc[i][j] += a[i] * b[j];
        }
        __syncthreads();
    }
    // scatter: col j -> s=j>>11, c=(j>>8)&7, d=j&255 ; row r -> b=r>>10, n=r&1023
#pragma unroll
    for (int i = 0; i < 8; i++) {
        int r = row0 + ty * 8 + i;
        int b = r >> 10, n = r & 1023;
#pragma unroll
        for (int j = 0; j < 8; j += 4) {
            int col = col0 + tx * 8 + j;
            int s = col >> 11;
            int c = (col >> 8) & 7;
            int d = col & 255;
            float* dst = (s ? kbuf : q) + (((size_t)(b * CC + c) * NN + n) * DD + d);
            *(float4*)dst = make_float4(acc[i][j], acc[i][j + 1], acc[i][j + 2], acc[i][j + 3]);
        }
    }
}

// ---------------------------------------------------------------------------
// Kernel 2: per z=(b*C+c): S = (q @ k^T) * scale  -> attn buffer [z][n][m]
// ---------------------------------------------------------------------------
__global__ __launch_bounds__(256) void gemm_qkt(const float* __restrict__ q,
                                                const float* __restrict__ kbuf,
                                                float* __restrict__ attn) {
    const int K = DD;
    const float scale = 0.0625f;  // 256^-0.5
    __shared__ float As[16][132];
    __shared__ float Bs[16][132];
    const int tid = threadIdx.x;
    const int tx = tid & 15, ty = tid >> 4;
    const int z = blockIdx.z;
    const float* A = q + (size_t)z * NN * DD;
    const float* Bm = kbuf + (size_t)z * NN * DD;
    float* Cm = attn + (size_t)z * NN * NN;
    const int row0 = blockIdx.y * 128, col0 = blockIdx.x * 128;

    float acc[8][8];
#pragma unroll
    for (int i = 0; i < 8; i++)
#pragma unroll
        for (int j = 0; j < 8; j++) acc[i][j] = 0.f;

    for (int k0 = 0; k0 < K; k0 += 16) {
        {   // q tile
            int r = tid >> 1;
            int kk = (tid & 1) * 8;
            const float* src = A + (size_t)(row0 + r) * K + k0 + kk;
            float4 v0 = *(const float4*)(src);
            float4 v1 = *(const float4*)(src + 4);
            As[kk + 0][r] = v0.x; As[kk + 1][r] = v0.y;
            As[kk + 2][r] = v0.z; As[kk + 3][r] = v0.w;
            As[kk + 4][r] = v1.x; As[kk + 5][r] = v1.y;
            As[kk + 6][r] = v1.z; As[kk + 7][r] = v1.w;
        }
        {   // k tile (rows of k, NT-gemm) — same transposed store
            int r = tid >> 1;
            int kk = (tid & 1) * 8;
            const float* src = Bm + (size_t)(col0 + r) * K + k0 + kk;
            float4 v0 = *(const float4*)(src);
            float4 v1 = *(const float4*)(src + 4);
            Bs[kk + 0][r] = v0.x; Bs[kk + 1][r] = v0.y;
            Bs[kk + 2][r] = v0.z; Bs[kk + 3][r] = v0.w;
            Bs[kk + 4][r] = v1.x; Bs[kk + 5][r] = v1.y;
            Bs[kk + 6][r] = v1.z; Bs[kk + 7][r] = v1.w;
        }
        __syncthreads();
#pragma unroll
        for (int kk = 0; kk < 16; kk++) {
            float a[8], b[8];
            *(float4*)&a[0] = *(float4*)&As[kk][ty * 8];
            *(float4*)&a[4] = *(float4*)&As[kk][ty * 8 + 4];
            *(float4*)&b[0] = *(float4*)&Bs[kk][tx * 8];
            *(float4*)&b[4] = *(float4*)&Bs[kk][tx * 8 + 4];
#pragma unroll
            for (int i = 0; i < 8; i++)
#pragma unroll
                for (int j = 0; j < 8; j++) acc[i][j] += a[i] * b[j];
        }
        __syncthreads();
    }
#pragma unroll
    for (int i = 0; i < 8; i++) {
        int r = row0 + ty * 8 + i;
#pragma unroll
        for (int j = 0; j < 8; j += 4) {
            int col = col0 + tx * 8 + j;
            *(float4*)(Cm + (size_t)r * NN + col) =
                make_float4(acc[i][j] * scale, acc[i][j + 1] * scale,
                            acc[i][j + 2] * scale, acc[i][j + 3] * scale);
        }
    }
}

// ---------------------------------------------------------------------------
// Kernel 3: row softmax in place. One block (256 thr) per row (grid 32768).
// ---------------------------------------------------------------------------
__global__ __launch_bounds__(256) void softmax_rows(float* __restrict__ attn) {
    __shared__ float red[256];
    float* p = attn + (size_t)blockIdx.x * NN;
    const int tid = threadIdx.x;
    float4 v = ((float4*)p)[tid];
    float mx = fmaxf(fmaxf(v.x, v.y), fmaxf(v.z, v.w));
    red[tid] = mx;
    __syncthreads();
    for (int s = 128; s > 0; s >>= 1) {
        if (tid < s) red[tid] = fmaxf(red[tid], red[tid + s]);
        __syncthreads();
    }
    float m = red[0];
    __syncthreads();
    float e0 = expf(v.x - m), e1 = expf(v.y - m), e2 = expf(v.z - m), e3 = expf(v.w - m);
    red[tid] = e0 + e1 + e2 + e3;
    __syncthreads();
    for (int s = 128; s > 0; s >>= 1) {
        if (tid < s) red[tid] += red[tid + s];
        __syncthreads();
    }
    float inv = 1.0f / red[0];
    ((float4*)p)[tid] = make_float4(e0 * inv, e1 * inv, e2 * inv, e3 * inv);
}

// ---------------------------------------------------------------------------
// Kernel 4: sum over channels -> sum_edge [B,N,N]. Block per (b,n).
// ---------------------------------------------------------------------------
__global__ __launch_bounds__(256) void chan_sum(const float* __restrict__ attn,
                                                float* __restrict__ sum_edge) {
    const int bn = blockIdx.x;           // b*1024+n
    const int b = bn >> 10, n = bn & 1023;
    const int m4 = threadIdx.x * 4;
    float4 s = make_float4(0.f, 0.f, 0.f, 0.f);
#pragma unroll
    for (int c = 0; c < CC; c++) {
        float4 v = *(const float4*)(attn + (((size_t)(b * CC + c) * NN + n) * NN + m4));
        s.x += v.x; s.y += v.y; s.z += v.z; s.w += v.w;
    }
    *(float4*)(sum_edge + (size_t)bn * NN + m4) = s;
}

// ---------------------------------------------------------------------------
// Kernel 5: top-16 of each sum_edge row (+ diagonal dedup). Block per (b,n).
// Tie-break: lower index (matches jax.lax.top_k).
// ---------------------------------------------------------------------------
__global__ __launch_bounds__(256) void topk16(const float* __restrict__ sum_edge,
                                              int* __restrict__ idx,
                                              int* __restrict__ cnt) {
    __shared__ float vals[NN];
    __shared__ float rv[256];
    __shared__ int ri[256];
    __shared__ int chosen[KNBR];
    const int bn = blockIdx.x;
    const int tid = threadIdx.x;
    ((float4*)vals)[tid] = ((const float4*)(sum_edge + (size_t)bn * NN))[tid];
    __syncthreads();
    for (int it = 0; it < KNBR; it++) {
        float bv = vals[tid * 4];
        int bi = tid * 4;
#pragma unroll
        for (int j = 1; j < 4; j++) {
            float x = vals[tid * 4 + j];
            if (x > bv) { bv = x; bi = tid * 4 + j; }
        }
        rv[tid] = bv; ri[tid] = bi;
        __syncthreads();
        for (int s = 128; s > 0; s >>= 1) {
            if (tid < s) {
                float xv = rv[tid + s]; int xi = ri[tid + s];
                if (xv > rv[tid] || (xv == rv[tid] && xi < ri[tid])) { rv[tid] = xv; ri[tid] = xi; }
            }
            __syncthreads();
        }
        if (tid == 0) { chosen[it] = ri[0]; vals[ri[0]] = -INFINITY; }
        __syncthreads();
    }
    if (tid == 0) {
        const int n = bn & 1023;
        bool has = false;
        for (int t = 0; t < KNBR; t++) {
            idx[bn * MAXSEL + t] = chosen[t];
            if (chosen[t] == n) has = true;
        }
        int c = KNBR;
        if (!has) { idx[bn * MAXSEL + KNBR] = n; c = KNBR + 1; }
        cnt[bn] = c;
    }
}

// ---------------------------------------------------------------------------
// Kernel 6: gather masked attn, row-normalize, accumulate column sums.
// One thread per (b,c,n) — 32768 threads.
// ---------------------------------------------------------------------------
__global__ __launch_bounds__(256) void rownorm(const float* __restrict__ attn,
                                               const int* __restrict__ idx,
                                               const int* __restrict__ cnt,
                                               float* __restrict__ nr,
                                               float* __restrict__ colsum) {
    const int t = blockIdx.x * 256 + threadIdx.x;  // (b*C+c)*N + n
    const int z = t >> 10, n = t & 1023;
    const int b = z >> 3;
    const int bn = b * NN + n;
    const int c_ = cnt[bn];
    const float* arow = attn + (size_t)t * NN;
    float a[MAXSEL];
    float s = 0.f;
#pragma unroll
    for (int j = 0; j < MAXSEL; j++) {
        if (j < c_) { a[j] = arow[idx[bn * MAXSEL + j]]; s += a[j]; }
        else a[j] = 0.f;
    }
    const float inv = 1.f / (s + 1e-6f);
#pragma unroll
    for (int j = 0; j < MAXSEL; j++) {
        if (j < c_) {
            float v = a[j] * inv;
            nr[(size_t)t * MAXSEL + j] = v;
            atomicAdd(&colsum[(size_t)z * NN + idx[bn * MAXSEL + j]], v);
        } else {
            nr[(size_t)t * MAXSEL + j] = 0.f;
        }
    }
}

// ---------------------------------------------------------------------------
// Kernel 7: scatter norm_col^T into dense NCT[z][k][m] (attn buffer, re-zeroed)
// NCT[k][m] = nr[m][j(k)] / (colsum[k]+1e-6)
// ---------------------------------------------------------------------------
__global__ __launch_bounds__(256) void scatter_nct(const float* __restrict__ nr,
                                                   const int* __restrict__ idx,
                                                   const int* __restrict__ cnt,
                                                   const float* __restrict__ colsum,
                                                   float* __restrict__ nct) {
    const int t = blockIdx.x * 256 + threadIdx.x;  // (b*C+c)*N + n
    const int z = t >> 10, n = t & 1023;
    const int b = z >> 3;
    const int bn = b * NN + n;
    const int c_ = cnt[bn];
#pragma unroll
    for (int j = 0; j < MAXSEL; j++) {
        if (j < c_) {
            int k = idx[bn * MAXSEL + j];
            float v = nr[(size_t)t * MAXSEL + j] / (colsum[(size_t)z * NN + k] + 1e-6f);
            nct[((size_t)z * NN + k) * NN + n] = v;
        }
    }
}

// ---------------------------------------------------------------------------
// Kernel 8: out[z][n][m] = sum_j nr[n][j] * NCT[k_j][m]. Block per (z,n).
// ---------------------------------------------------------------------------
__global__ __launch_bounds__(256) void out_rows(const float* __restrict__ nr,
                                                const int* __restrict__ idx,
                                                const int* __restrict__ cnt,
                                                const float* __restrict__ nct,
                                                float* __restrict__ out) {
    __shared__ float snr[MAXSEL];
    __shared__ int sk[MAXSEL];
    __shared__ int scnt;
    const int t = blockIdx.x;  // (b*C+c)*N + n
    const int z = t >> 10, n = t & 1023;
    const int b = z >> 3;
    const int bn = b * NN + n;
    const int tid = threadIdx.x;
    if (tid < MAXSEL) {
        snr[tid] = nr[(size_t)t * MAXSEL + tid];
        sk[tid] = idx[bn * MAXSEL + tid];
    }
    if (tid == 0) scnt = cnt[bn];
    __syncthreads();
    const int m4 = tid * 4;
    float4 acc = make_float4(0.f, 0.f, 0.f, 0.f);
    const int c_ = scnt;
    for (int j = 0; j < c_; j++) {
        const float w = snr[j];
        float4 v = *(const float4*)(nct + ((size_t)z * NN + sk[j]) * NN + m4);
        acc.x += w * v.x; acc.y += w * v.y; acc.z += w * v.z; acc.w += w * v.w;
    }
    *(float4*)(out + (size_t)t * NN + m4) = acc;
}

// ---------------------------------------------------------------------------
extern "C" void kernel_launch(void* const* d_in, const int* in_sizes, int n_in,
                              void* d_out, int out_size, void* d_ws, size_t ws_size,
                              hipStream_t stream) {
    const float* x = (const float*)d_in[0];    // [4,1024,256]
    const float* W = (const float*)d_in[1];    // [256,4096]
    float* out = (float*)d_out;                // [4,8,1024,1024]
    char* ws = (char*)d_ws;

    // workspace layout (bytes)
    float* q        = (float*)(ws);                       // 33,554,432 B
    float* kbuf     = (float*)(ws + 33554432ull);         // 33,554,432 B
    float* attn     = (float*)(ws + 67108864ull);         // 134,217,728 B (reused as NCT)
    float* sum_edge = (float*)(ws + 201326592ull);        // 16,777,216 B
    int*   idx      = (int*)  (ws + 218103808ull);        // 278,528 B
    int*   cnt      = (int*)  (ws + 218382336ull);        // 16,384 B
    float* nr       = (float*)(ws + 218398720ull);        // 2,228,224 B
    float* colsum   = (float*)(ws + 220626944ull);        // 131,072 B

    gemm_xw<<<dim3(32, 32), 256, 0, stream>>>(x, W, q, kbuf);
    gemm_qkt<<<dim3(8, 8, 32), 256, 0, stream>>>(q, kbuf, attn);
    softmax_rows<<<32768, 256, 0, stream>>>(attn);
    chan_sum<<<4096, 256, 0, stream>>>(attn, sum_edge);
    topk16<<<4096, 256, 0, stream>>>(sum_edge, idx, cnt);
    hipMemsetAsync(colsum, 0, 131072, stream);
    rownorm<<<128, 256, 0, stream>>>(attn, idx, cnt, nr, colsum);
    // attn no longer needed as attention — re-zero and reuse as dense NCT
    hipMemsetAsync(attn, 0, 134217728ull, stream);
    scatter_nct<<<128, 256, 0, stream>>>(nr, idx, cnt, colsum, attn);
    out_rows<<<32768, 256, 0, stream>>>(nr, idx, cnt, attn, out);
}

// Round 3
// 580.081 us; speedup vs baseline: 1.2816x; 1.2816x over previous
//
#include <hip/hip_runtime.h>
#include <hip/hip_bf16.h>
#include <math.h>

// Problem constants
#define BB 4
#define NN 1024
#define DD 256
#define CC 8
#define KNBR 16
#define MAXSEL 17   // 16 top-k + possibly the diagonal

typedef __bf16 bf16x8_t __attribute__((ext_vector_type(8)));
typedef float  f32x4_t  __attribute__((ext_vector_type(4)));

// async global->LDS, 16 bytes per lane. ldsbase must be wave-uniform
// (HW places lane i at ldsbase + i*16).
__device__ __forceinline__ void gl2lds16(const __bf16* g, __bf16* ldsbase) {
    __builtin_amdgcn_global_load_lds(
        (const __attribute__((address_space(1))) unsigned int*)g,
        (__attribute__((address_space(3))) unsigned int*)ldsbase, 16, 0, 0);
}

// 3-level bf16 split: v = h + m + l + eps, |eps| <= 2^-24 |v|
// (r = v - h and r - m are Sterbenz-exact in fp32)
__device__ __forceinline__ void split3(float v, __bf16& h, __bf16& m, __bf16& l) {
    h = (__bf16)v;
    float r = v - (float)h;
    m = (__bf16)r;
    l = (__bf16)(r - (float)m);
}

// ---------------------------------------------------------------------------
// Kernel 0a: split x (fp32 [4096,256]) into 3 bf16 components
// ---------------------------------------------------------------------------
__global__ __launch_bounds__(256) void split_x(const float* __restrict__ x,
                                               __bf16* __restrict__ xh,
                                               __bf16* __restrict__ xm,
                                               __bf16* __restrict__ xl) {
    int i = (blockIdx.x * 256 + threadIdx.x) * 4;
    float4 v = *(const float4*)(x + i);
    __bf16 h0, m0, l0, h1, m1, l1, h2, m2, l2, h3, m3, l3;
    split3(v.x, h0, m0, l0);
    split3(v.y, h1, m1, l1);
    split3(v.z, h2, m2, l2);
    split3(v.w, h3, m3, l3);
    xh[i] = h0; xh[i + 1] = h1; xh[i + 2] = h2; xh[i + 3] = h3;
    xm[i] = m0; xm[i + 1] = m1; xm[i + 2] = m2; xm[i + 3] = m3;
    xl[i] = l0; xl[i + 1] = l1; xl[i + 2] = l2; xl[i + 3] = l3;
}

// ---------------------------------------------------------------------------
// Kernel 0b: transpose + split W [256,4096] -> Wt comps [4096,256]
// ---------------------------------------------------------------------------
__global__ __launch_bounds__(256) void split_wt(const float* __restrict__ W,
                                                __bf16* __restrict__ Wth,
                                                __bf16* __restrict__ Wtm,
                                                __bf16* __restrict__ Wtl) {
    __shared__ float t[64][65];
    const int tid = threadIdx.x;
    const int n0 = blockIdx.x * 64;
    const int k0 = blockIdx.y * 64;
#pragma unroll
    for (int i = 0; i < 16; i++) {
        int k = i * 4 + (tid >> 6);
        int n = tid & 63;
        t[k][n] = W[(size_t)(k0 + k) * 4096 + n0 + n];
    }
    __syncthreads();
#pragma unroll
    for (int i = 0; i < 16; i++) {
        int n = i * 4 + (tid >> 6);
        int k = tid & 63;
        __bf16 h, m, l;
        split3(t[k][n], h, m, l);
        size_t o = (size_t)(n0 + n) * 256 + k0 + k;
        Wth[o] = h; Wtm[o] = m; Wtl[o] = l;
    }
}

// stage one 128x32 bf16 tile (rows rowbase..rowbase+127, cols k0..k0+31)
#define STAGE1(dst, src, rowbase)                                              \
    do {                                                                       \
        gl2lds16(src + (size_t)((rowbase) + r_st) * 256 + k0 + c8,             \
                 &dst[(w * 64) * 8]);                                          \
        gl2lds16(src + (size_t)((rowbase) + 64 + r_st) * 256 + k0 + c8,        \
                 &dst[(256 + w * 64) * 8]);                                    \
    } while (0)

// 6-term product ladder, smallest first (hh last)
#define MFMA6(accv, AH, AM, AL, BH, BM, BL)                                    \
    do {                                                                       \
        accv = __builtin_amdgcn_mfma_f32_16x16x32_bf16(AL, BH, accv, 0, 0, 0); \
        accv = __builtin_amdgcn_mfma_f32_16x16x32_bf16(AH, BL, accv, 0, 0, 0); \
        accv = __builtin_amdgcn_mfma_f32_16x16x32_bf16(AM, BM, accv, 0, 0, 0); \
        accv = __builtin_amdgcn_mfma_f32_16x16x32_bf16(AM, BH, accv, 0, 0, 0); \
        accv = __builtin_amdgcn_mfma_f32_16x16x32_bf16(AH, BM, accv, 0, 0, 0); \
        accv = __builtin_amdgcn_mfma_f32_16x16x32_bf16(AH, BH, accv, 0, 0, 0); \
    } while (0)

// ---------------------------------------------------------------------------
// Kernel 1: qk = x @ W via 6-term bf16x3 MFMA; epilogue 3-splits into q/k.
// ---------------------------------------------------------------------------
__global__ __launch_bounds__(256) void gemm_xw_mfma(
        const __bf16* __restrict__ xh, const __bf16* __restrict__ xm,
        const __bf16* __restrict__ xl, const __bf16* __restrict__ wth,
        const __bf16* __restrict__ wtm, const __bf16* __restrict__ wtl,
        __bf16* __restrict__ qh, __bf16* __restrict__ qm, __bf16* __restrict__ ql,
        __bf16* __restrict__ kh, __bf16* __restrict__ km, __bf16* __restrict__ kl) {
    __shared__ __bf16 Ah[128 * 32], Am[128 * 32], Al[128 * 32];
    __shared__ __bf16 Bh[128 * 32], Bm[128 * 32], Bl[128 * 32];
    const int tid = threadIdx.x, lane = tid & 63, w = tid >> 6;
    const int wr = w >> 1, wc = w & 1;
    const int lm = lane & 15, quad = lane >> 4;
    const int row0 = blockIdx.y * 128, col0 = blockIdx.x * 128;
    const int r_st = tid >> 2;
    const int c8 = (tid & 3) * 8;

    f32x4_t acc[4][4];
#pragma unroll
    for (int i = 0; i < 4; i++)
#pragma unroll
        for (int j = 0; j < 4; j++) acc[i][j] = (f32x4_t)(0.f);

    for (int k0 = 0; k0 < 256; k0 += 32) {
        __syncthreads();
        STAGE1(Ah, xh, row0); STAGE1(Am, xm, row0); STAGE1(Al, xl, row0);
        STAGE1(Bh, wth, col0); STAGE1(Bm, wtm, col0); STAGE1(Bl, wtl, col0);
        __syncthreads();

        bf16x8_t ah[4], am[4], al[4];
#pragma unroll
        for (int mi = 0; mi < 4; mi++) {
            int r = (wr * 64 + mi * 16 + lm) * 32 + quad * 8;
            ah[mi] = *(const bf16x8_t*)&Ah[r];
            am[mi] = *(const bf16x8_t*)&Am[r];
            al[mi] = *(const bf16x8_t*)&Al[r];
        }
#pragma unroll
        for (int ni = 0; ni < 4; ni++) {
            int rb = (wc * 64 + ni * 16 + lm) * 32 + quad * 8;
            bf16x8_t bh = *(const bf16x8_t*)&Bh[rb];
            bf16x8_t bm = *(const bf16x8_t*)&Bm[rb];
            bf16x8_t bl = *(const bf16x8_t*)&Bl[rb];
#pragma unroll
            for (int mi = 0; mi < 4; mi++)
                MFMA6(acc[mi][ni], ah[mi], am[mi], al[mi], bh, bm, bl);
        }
    }

    // epilogue: 3-split fp32 result, scatter to q or k comps [B,C,N,D]
#pragma unroll
    for (int mi = 0; mi < 4; mi++)
#pragma unroll
        for (int ni = 0; ni < 4; ni++) {
            int row = row0 + wr * 64 + mi * 16 + quad * 4;
            int col = col0 + wc * 64 + ni * 16 + lm;
            int s = col >> 11, c = (col >> 8) & 7, d = col & 255;
            __bf16* dh = s ? kh : qh;
            __bf16* dm = s ? km : qm;
            __bf16* dl = s ? kl : ql;
#pragma unroll
            for (int r = 0; r < 4; r++) {
                int rr = row + r;
                int b = rr >> 10, n = rr & 1023;
                size_t o = (((size_t)(b * CC + c)) * NN + n) * DD + d;
                __bf16 h, m, l;
                split3(acc[mi][ni][r], h, m, l);
                dh[o] = h; dm[o] = m; dl[o] = l;
            }
        }
}

// ---------------------------------------------------------------------------
// Kernel 2: per z: attn = (q @ k^T) * scale via 6-term bf16x3 MFMA.
// ---------------------------------------------------------------------------
__global__ __launch_bounds__(256) void gemm_qkt_mfma(
        const __bf16* __restrict__ qh, const __bf16* __restrict__ qm,
        const __bf16* __restrict__ ql, const __bf16* __restrict__ kh,
        const __bf16* __restrict__ km, const __bf16* __restrict__ kl,
        float* __restrict__ attn) {
    __shared__ __bf16 Ah[128 * 32], Am[128 * 32], Al[128 * 32];
    __shared__ __bf16 Bh[128 * 32], Bm[128 * 32], Bl[128 * 32];
    const int tid = threadIdx.x, lane = tid & 63, w = tid >> 6;
    const int wr = w >> 1, wc = w & 1;
    const int lm = lane & 15, quad = lane >> 4;
    const int z = blockIdx.z;
    const size_t zo = (size_t)z * NN * DD;
    float* Cm = attn + (size_t)z * NN * NN;
    const int row0 = blockIdx.y * 128, col0 = blockIdx.x * 128;
    const int r_st = tid >> 2;
    const int c8 = (tid & 3) * 8;
    const float scale = 0.0625f;  // 256^-0.5

    f32x4_t acc[4][4];
#pragma unroll
    for (int i = 0; i < 4; i++)
#pragma unroll
        for (int j = 0; j < 4; j++) acc[i][j] = (f32x4_t)(0.f);

    for (int k0 = 0; k0 < 256; k0 += 32) {
        __syncthreads();
        STAGE1(Ah, (qh + zo), row0); STAGE1(Am, (qm + zo), row0); STAGE1(Al, (ql + zo), row0);
        STAGE1(Bh, (kh + zo), col0); STAGE1(Bm, (km + zo), col0); STAGE1(Bl, (kl + zo), col0);
        __syncthreads();

        bf16x8_t ah[4], am[4], al[4];
#pragma unroll
        for (int mi = 0; mi < 4; mi++) {
            int r = (wr * 64 + mi * 16 + lm) * 32 + quad * 8;
            ah[mi] = *(const bf16x8_t*)&Ah[r];
            am[mi] = *(const bf16x8_t*)&Am[r];
            al[mi] = *(const bf16x8_t*)&Al[r];
        }
#pragma unroll
        for (int ni = 0; ni < 4; ni++) {
            int rb = (wc * 64 + ni * 16 + lm) * 32 + quad * 8;
            bf16x8_t bh = *(const bf16x8_t*)&Bh[rb];
            bf16x8_t bm = *(const bf16x8_t*)&Bm[rb];
            bf16x8_t bl = *(const bf16x8_t*)&Bl[rb];
#pragma unroll
            for (int mi = 0; mi < 4; mi++)
                MFMA6(acc[mi][ni], ah[mi], am[mi], al[mi], bh, bm, bl);
        }
    }

#pragma unroll
    for (int mi = 0; mi < 4; mi++)
#pragma unroll
        for (int ni = 0; ni < 4; ni++) {
            int row = row0 + wr * 64 + mi * 16 + quad * 4;
            int col = col0 + wc * 64 + ni * 16 + lm;
#pragma unroll
            for (int r = 0; r < 4; r++)
                Cm[(size_t)(row + r) * NN + col] = acc[mi][ni][r] * scale;
        }
}

// ---------------------------------------------------------------------------
// Kernel 3: fused per-(b,n): softmax over all 8 channel rows (in regs),
// channel-sum, top-16 selection. Writes normalized attn + idx/cnt.
// ---------------------------------------------------------------------------
__global__ __launch_bounds__(256) void softmax_topk(float* __restrict__ attn,
                                                    int* __restrict__ idx,
                                                    int* __restrict__ cnt) {
    __shared__ float sum[NN];
    __shared__ float wsc[CC][8];
    __shared__ float tv[4];
    __shared__ int ti[4];
    __shared__ int chosen[KNBR];
    const int bn = blockIdx.x, b = bn >> 10, n = bn & 1023;
    const int tid = threadIdx.x, lane = tid & 63, w = tid >> 6;
    const int m4 = tid * 4;

    float4 v[CC];
#pragma unroll
    for (int c = 0; c < CC; c++)
        v[c] = *(const float4*)(attn + (((size_t)(b * CC + c) * NN + n) * NN + m4));

    float4 s4 = make_float4(0.f, 0.f, 0.f, 0.f);
#pragma unroll
    for (int c = 0; c < CC; c++) {
        float mx = fmaxf(fmaxf(v[c].x, v[c].y), fmaxf(v[c].z, v[c].w));
#pragma unroll
        for (int off = 32; off; off >>= 1) mx = fmaxf(mx, __shfl_down(mx, off));
        if (lane == 0) wsc[c][w] = mx;
        __syncthreads();
        mx = fmaxf(fmaxf(wsc[c][0], wsc[c][1]), fmaxf(wsc[c][2], wsc[c][3]));
        v[c].x = expf(v[c].x - mx);
        v[c].y = expf(v[c].y - mx);
        v[c].z = expf(v[c].z - mx);
        v[c].w = expf(v[c].w - mx);
        float sm = v[c].x + v[c].y + v[c].z + v[c].w;
#pragma unroll
        for (int off = 32; off; off >>= 1) sm += __shfl_down(sm, off);
        if (lane == 0) wsc[c][4 + w] = sm;
        __syncthreads();
        float inv = 1.0f / (wsc[c][4] + wsc[c][5] + wsc[c][6] + wsc[c][7]);
        v[c].x *= inv; v[c].y *= inv; v[c].z *= inv; v[c].w *= inv;
        s4.x += v[c].x; s4.y += v[c].y; s4.z += v[c].z; s4.w += v[c].w;
        *(float4*)(attn + (((size_t)(b * CC + c) * NN + n) * NN + m4)) = v[c];
    }
    *(float4*)&sum[m4] = s4;
    __syncthreads();

    for (int it = 0; it < KNBR; it++) {
        float bv = sum[m4]; int bi = m4;
#pragma unroll
        for (int j = 1; j < 4; j++) {
            float x = sum[m4 + j];
            if (x > bv) { bv = x; bi = m4 + j; }
        }
#pragma unroll
        for (int off = 32; off; off >>= 1) {
            float ov = __shfl_down(bv, off);
            int oi = __shfl_down(bi, off);
            if (ov > bv || (ov == bv && oi < bi)) { bv = ov; bi = oi; }
        }
        if (lane == 0) { tv[w] = bv; ti[w] = bi; }
        __syncthreads();
        if (tid == 0) {
            float cv = tv[0]; int ci = ti[0];
#pragma unroll
            for (int k = 1; k < 4; k++)
                if (tv[k] > cv || (tv[k] == cv && ti[k] < ci)) { cv = tv[k]; ci = ti[k]; }
            chosen[it] = ci;
            sum[ci] = -INFINITY;
        }
        __syncthreads();
    }
    if (tid == 0) {
        bool has = false;
        for (int t = 0; t < KNBR; t++) {
            idx[bn * MAXSEL + t] = chosen[t];
            if (chosen[t] == n) has = true;
        }
        int c = KNBR;
        if (!has) { idx[bn * MAXSEL + KNBR] = n; c = KNBR + 1; }
        cnt[bn] = c;
    }
}

// ---------------------------------------------------------------------------
// Kernel 4: gather masked attn, row-normalize, accumulate column sums.
// ---------------------------------------------------------------------------
__global__ __launch_bounds__(256) void rownorm(const float* __restrict__ attn,
                                               const int* __restrict__ idx,
                                               const int* __restrict__ cnt,
                                               float* __restrict__ nr,
                                               float* __restrict__ colsum) {
    const int t = blockIdx.x * 256 + threadIdx.x;
    const int z = t >> 10, n = t & 1023;
    const int b = z >> 3;
    const int bn = b * NN + n;
    const int c_ = cnt[bn];
    const float* arow = attn + (size_t)t * NN;
    float a[MAXSEL];
    float s = 0.f;
#pragma unroll
    for (int j = 0; j < MAXSEL; j++) {
        if (j < c_) { a[j] = arow[idx[bn * MAXSEL + j]]; s += a[j]; }
        else a[j] = 0.f;
    }
    const float inv = 1.f / (s + 1e-6f);
#pragma unroll
    for (int j = 0; j < MAXSEL; j++) {
        if (j < c_) {
            float v = a[j] * inv;
            nr[(size_t)t * MAXSEL + j] = v;
            atomicAdd(&colsum[(size_t)z * NN + idx[bn * MAXSEL + j]], v);
        } else {
            nr[(size_t)t * MAXSEL + j] = 0.f;
        }
    }
}

// ---------------------------------------------------------------------------
// Kernel 5: scatter norm_col^T into dense NCT (zeroed q/k region reuse).
// ---------------------------------------------------------------------------
__global__ __launch_bounds__(256) void scatter_nct(const float* __restrict__ nr,
                                                   const int* __restrict__ idx,
                                                   const int* __restrict__ cnt,
                                                   const float* __restrict__ colsum,
                                                   float* __restrict__ nct) {
    const int t = blockIdx.x * 256 + threadIdx.x;
    const int z = t >> 10, n = t & 1023;
    const int b = z >> 3;
    const int bn = b * NN + n;
    const int c_ = cnt[bn];
#pragma unroll
    for (int j = 0; j < MAXSEL; j++) {
        if (j < c_) {
            int k = idx[bn * MAXSEL + j];
            float v = nr[(size_t)t * MAXSEL + j] / (colsum[(size_t)z * NN + k] + 1e-6f);
            nct[((size_t)z * NN + k) * NN + n] = v;
        }
    }
}

// ---------------------------------------------------------------------------
// Kernel 6: out[z][n][m] = sum_j nr[n][j] * NCT[k_j][m]. Block per (z,n).
// ---------------------------------------------------------------------------
__global__ __launch_bounds__(256) void out_rows(const float* __restrict__ nr,
                                                const int* __restrict__ idx,
                                                const int* __restrict__ cnt,
                                                const float* __restrict__ nct,
                                                float* __restrict__ out) {
    __shared__ float snr[MAXSEL];
    __shared__ int sk[MAXSEL];
    __shared__ int scnt;
    const int t = blockIdx.x;
    const int z = t >> 10, n = t & 1023;
    const int b = z >> 3;
    const int bn = b * NN + n;
    const int tid = threadIdx.x;
    if (tid < MAXSEL) {
        snr[tid] = nr[(size_t)t * MAXSEL + tid];
        sk[tid] = idx[bn * MAXSEL + tid];
    }
    if (tid == 0) scnt = cnt[bn];
    __syncthreads();
    const int m4 = tid * 4;
    float4 acc = make_float4(0.f, 0.f, 0.f, 0.f);
    const int c_ = scnt;
    for (int j = 0; j < c_; j++) {
        const float w = snr[j];
        float4 v = *(const float4*)(nct + ((size_t)z * NN + sk[j]) * NN + m4);
        acc.x += w * v.x; acc.y += w * v.y; acc.z += w * v.z; acc.w += w * v.w;
    }
    *(float4*)(out + (size_t)t * NN + m4) = acc;
}

// ---------------------------------------------------------------------------
extern "C" void kernel_launch(void* const* d_in, const int* in_sizes, int n_in,
                              void* d_out, int out_size, void* d_ws, size_t ws_size,
                              hipStream_t stream) {
    const float* x = (const float*)d_in[0];    // [4,1024,256]
    const float* W = (const float*)d_in[1];    // [256,4096]
    float* out = (float*)d_out;                // [4,8,1024,1024]
    char* ws = (char*)d_ws;

    // attn lives in d_out (134,217,728 B == out size); d_out is dead until
    // out_rows rewrites every element at the end.
    float* attn = (float*)d_out;

    // workspace layout (bytes) — phase 1: q/k comps + x/W splits; after the
    // qkt GEMM the first 134,217,728 B are re-zeroed and reused as NCT.
    __bf16* qh  = (__bf16*)(ws);
    __bf16* qm  = (__bf16*)(ws + 16777216ull);
    __bf16* ql  = (__bf16*)(ws + 33554432ull);
    __bf16* kh  = (__bf16*)(ws + 50331648ull);
    __bf16* km  = (__bf16*)(ws + 67108864ull);
    __bf16* kl  = (__bf16*)(ws + 83886080ull);
    __bf16* xh  = (__bf16*)(ws + 100663296ull);
    __bf16* xm  = (__bf16*)(ws + 102760448ull);
    __bf16* xl  = (__bf16*)(ws + 104857600ull);
    __bf16* wth = (__bf16*)(ws + 106954752ull);
    __bf16* wtm = (__bf16*)(ws + 109051904ull);
    __bf16* wtl = (__bf16*)(ws + 111149056ull);
    float*  nct = (float*)(ws);                        // 134,217,728 (reuse)
    int*    idx = (int*)  (ws + 134217728ull);         // 278,528
    int*    cnt = (int*)  (ws + 134496256ull);         // 16,384
    float*  nr  = (float*)(ws + 134512640ull);         // 2,228,224
    float*  colsum = (float*)(ws + 136740864ull);      // 131,072

    split_x<<<1024, 256, 0, stream>>>(x, xh, xm, xl);
    split_wt<<<dim3(64, 4), 256, 0, stream>>>(W, wth, wtm, wtl);
    gemm_xw_mfma<<<dim3(32, 32), 256, 0, stream>>>(xh, xm, xl, wth, wtm, wtl,
                                                   qh, qm, ql, kh, km, kl);
    gemm_qkt_mfma<<<dim3(8, 8, 32), 256, 0, stream>>>(qh, qm, ql, kh, km, kl, attn);
    softmax_topk<<<4096, 256, 0, stream>>>(attn, idx, cnt);
    hipMemsetAsync(colsum, 0, 131072, stream);
    rownorm<<<128, 256, 0, stream>>>(attn, idx, cnt, nr, colsum);
    hipMemsetAsync(nct, 0, 134217728ull, stream);  // q/k comps dead now
    scatter_nct<<<128, 256, 0, stream>>>(nr, idx, cnt, colsum, nct);
    out_rows<<<32768, 256, 0, stream>>>(nr, idx, cnt, nct, out);
}

// Round 4
// 526.933 us; speedup vs baseline: 1.4108x; 1.1009x over previous
//
#include <hip/hip_runtime.h>
#include <hip/hip_bf16.h>
#include <math.h>

// Problem constants
#define BB 4
#define NN 1024
#define DD 256
#define CC 8
#define KNBR 16
#define MAXSEL 17   // 16 top-k + possibly the diagonal
#define ZCAP (NN * MAXSEL)   // 17408 max CSR entries per z

typedef __bf16 bf16x8_t __attribute__((ext_vector_type(8)));
typedef float  f32x4_t  __attribute__((ext_vector_type(4)));

// async global->LDS, 16 bytes per lane. ldsbase must be wave-uniform
// (HW places lane i at ldsbase + i*16).
__device__ __forceinline__ void gl2lds16(const __bf16* g, __bf16* ldsbase) {
    __builtin_amdgcn_global_load_lds(
        (const __attribute__((address_space(1))) unsigned int*)g,
        (__attribute__((address_space(3))) unsigned int*)ldsbase, 16, 0, 0);
}

// 3-level bf16 split: v = h + m + l + eps, |eps| <= 2^-24 |v|
__device__ __forceinline__ void split3(float v, __bf16& h, __bf16& m, __bf16& l) {
    h = (__bf16)v;
    float r = v - (float)h;
    m = (__bf16)r;
    l = (__bf16)(r - (float)m);
}

// ---------------------------------------------------------------------------
// Kernel 0a: split x (fp32 [4096,256]) into 3 bf16 components
// ---------------------------------------------------------------------------
__global__ __launch_bounds__(256) void split_x(const float* __restrict__ x,
                                               __bf16* __restrict__ xh,
                                               __bf16* __restrict__ xm,
                                               __bf16* __restrict__ xl) {
    int i = (blockIdx.x * 256 + threadIdx.x) * 4;
    float4 v = *(const float4*)(x + i);
    __bf16 h0, m0, l0, h1, m1, l1, h2, m2, l2, h3, m3, l3;
    split3(v.x, h0, m0, l0);
    split3(v.y, h1, m1, l1);
    split3(v.z, h2, m2, l2);
    split3(v.w, h3, m3, l3);
    xh[i] = h0; xh[i + 1] = h1; xh[i + 2] = h2; xh[i + 3] = h3;
    xm[i] = m0; xm[i + 1] = m1; xm[i + 2] = m2; xm[i + 3] = m3;
    xl[i] = l0; xl[i + 1] = l1; xl[i + 2] = l2; xl[i + 3] = l3;
}

// ---------------------------------------------------------------------------
// Kernel 0b: transpose + split W [256,4096] -> Wt comps [4096,256]
// ---------------------------------------------------------------------------
__global__ __launch_bounds__(256) void split_wt(const float* __restrict__ W,
                                                __bf16* __restrict__ Wth,
                                                __bf16* __restrict__ Wtm,
                                                __bf16* __restrict__ Wtl) {
    __shared__ float t[64][65];
    const int tid = threadIdx.x;
    const int n0 = blockIdx.x * 64;
    const int k0 = blockIdx.y * 64;
#pragma unroll
    for (int i = 0; i < 16; i++) {
        int k = i * 4 + (tid >> 6);
        int n = tid & 63;
        t[k][n] = W[(size_t)(k0 + k) * 4096 + n0 + n];
    }
    __syncthreads();
#pragma unroll
    for (int i = 0; i < 16; i++) {
        int n = i * 4 + (tid >> 6);
        int k = tid & 63;
        __bf16 h, m, l;
        split3(t[k][n], h, m, l);
        size_t o = (size_t)(n0 + n) * 256 + k0 + k;
        Wth[o] = h; Wtm[o] = m; Wtl[o] = l;
    }
}

// stage one 128x32 bf16 tile
#define STAGE1(dst, src, rowbase)                                              \
    do {                                                                       \
        gl2lds16(src + (size_t)((rowbase) + r_st) * 256 + k0 + c8,             \
                 &dst[(w * 64) * 8]);                                          \
        gl2lds16(src + (size_t)((rowbase) + 64 + r_st) * 256 + k0 + c8,        \
                 &dst[(256 + w * 64) * 8]);                                    \
    } while (0)

// 6-term product ladder, smallest first (hh last)
#define MFMA6(accv, AH, AM, AL, BH, BM, BL)                                    \
    do {                                                                       \
        accv = __builtin_amdgcn_mfma_f32_16x16x32_bf16(AL, BH, accv, 0, 0, 0); \
        accv = __builtin_amdgcn_mfma_f32_16x16x32_bf16(AH, BL, accv, 0, 0, 0); \
        accv = __builtin_amdgcn_mfma_f32_16x16x32_bf16(AM, BM, accv, 0, 0, 0); \
        accv = __builtin_amdgcn_mfma_f32_16x16x32_bf16(AM, BH, accv, 0, 0, 0); \
        accv = __builtin_amdgcn_mfma_f32_16x16x32_bf16(AH, BM, accv, 0, 0, 0); \
        accv = __builtin_amdgcn_mfma_f32_16x16x32_bf16(AH, BH, accv, 0, 0, 0); \
    } while (0)

// ---------------------------------------------------------------------------
// Kernel 1: qk = x @ W via 6-term bf16x3 MFMA; epilogue 3-splits into q/k.
// ---------------------------------------------------------------------------
__global__ __launch_bounds__(256) void gemm_xw_mfma(
        const __bf16* __restrict__ xh, const __bf16* __restrict__ xm,
        const __bf16* __restrict__ xl, const __bf16* __restrict__ wth,
        const __bf16* __restrict__ wtm, const __bf16* __restrict__ wtl,
        __bf16* __restrict__ qh, __bf16* __restrict__ qm, __bf16* __restrict__ ql,
        __bf16* __restrict__ kh, __bf16* __restrict__ km, __bf16* __restrict__ kl) {
    __shared__ __bf16 Ah[128 * 32], Am[128 * 32], Al[128 * 32];
    __shared__ __bf16 Bh[128 * 32], Bm[128 * 32], Bl[128 * 32];
    const int tid = threadIdx.x, lane = tid & 63, w = tid >> 6;
    const int wr = w >> 1, wc = w & 1;
    const int lm = lane & 15, quad = lane >> 4;
    const int row0 = blockIdx.y * 128, col0 = blockIdx.x * 128;
    const int r_st = tid >> 2;
    const int c8 = (tid & 3) * 8;

    f32x4_t acc[4][4];
#pragma unroll
    for (int i = 0; i < 4; i++)
#pragma unroll
        for (int j = 0; j < 4; j++) acc[i][j] = (f32x4_t)(0.f);

    for (int k0 = 0; k0 < 256; k0 += 32) {
        __syncthreads();
        STAGE1(Ah, xh, row0); STAGE1(Am, xm, row0); STAGE1(Al, xl, row0);
        STAGE1(Bh, wth, col0); STAGE1(Bm, wtm, col0); STAGE1(Bl, wtl, col0);
        __syncthreads();

        bf16x8_t ah[4], am[4], al[4];
#pragma unroll
        for (int mi = 0; mi < 4; mi++) {
            int r = (wr * 64 + mi * 16 + lm) * 32 + quad * 8;
            ah[mi] = *(const bf16x8_t*)&Ah[r];
            am[mi] = *(const bf16x8_t*)&Am[r];
            al[mi] = *(const bf16x8_t*)&Al[r];
        }
#pragma unroll
        for (int ni = 0; ni < 4; ni++) {
            int rb = (wc * 64 + ni * 16 + lm) * 32 + quad * 8;
            bf16x8_t bh = *(const bf16x8_t*)&Bh[rb];
            bf16x8_t bm = *(const bf16x8_t*)&Bm[rb];
            bf16x8_t bl = *(const bf16x8_t*)&Bl[rb];
#pragma unroll
            for (int mi = 0; mi < 4; mi++)
                MFMA6(acc[mi][ni], ah[mi], am[mi], al[mi], bh, bm, bl);
        }
    }

#pragma unroll
    for (int mi = 0; mi < 4; mi++)
#pragma unroll
        for (int ni = 0; ni < 4; ni++) {
            int row = row0 + wr * 64 + mi * 16 + quad * 4;
            int col = col0 + wc * 64 + ni * 16 + lm;
            int s = col >> 11, c = (col >> 8) & 7, d = col & 255;
            __bf16* dh = s ? kh : qh;
            __bf16* dm = s ? km : qm;
            __bf16* dl = s ? kl : ql;
#pragma unroll
            for (int r = 0; r < 4; r++) {
                int rr = row + r;
                int b = rr >> 10, n = rr & 1023;
                size_t o = (((size_t)(b * CC + c)) * NN + n) * DD + d;
                __bf16 h, m, l;
                split3(acc[mi][ni][r], h, m, l);
                dh[o] = h; dm[o] = m; dl[o] = l;
            }
        }
}

// ---------------------------------------------------------------------------
// Kernel 2: per z: attn = (q @ k^T) * scale via 6-term bf16x3 MFMA.
// ---------------------------------------------------------------------------
__global__ __launch_bounds__(256) void gemm_qkt_mfma(
        const __bf16* __restrict__ qh, const __bf16* __restrict__ qm,
        const __bf16* __restrict__ ql, const __bf16* __restrict__ kh,
        const __bf16* __restrict__ km, const __bf16* __restrict__ kl,
        float* __restrict__ attn) {
    __shared__ __bf16 Ah[128 * 32], Am[128 * 32], Al[128 * 32];
    __shared__ __bf16 Bh[128 * 32], Bm[128 * 32], Bl[128 * 32];
    const int tid = threadIdx.x, lane = tid & 63, w = tid >> 6;
    const int wr = w >> 1, wc = w & 1;
    const int lm = lane & 15, quad = lane >> 4;
    const int z = blockIdx.z;
    const size_t zo = (size_t)z * NN * DD;
    float* Cm = attn + (size_t)z * NN * NN;
    const int row0 = blockIdx.y * 128, col0 = blockIdx.x * 128;
    const int r_st = tid >> 2;
    const int c8 = (tid & 3) * 8;
    const float scale = 0.0625f;

    f32x4_t acc[4][4];
#pragma unroll
    for (int i = 0; i < 4; i++)
#pragma unroll
        for (int j = 0; j < 4; j++) acc[i][j] = (f32x4_t)(0.f);

    for (int k0 = 0; k0 < 256; k0 += 32) {
        __syncthreads();
        STAGE1(Ah, (qh + zo), row0); STAGE1(Am, (qm + zo), row0); STAGE1(Al, (ql + zo), row0);
        STAGE1(Bh, (kh + zo), col0); STAGE1(Bm, (km + zo), col0); STAGE1(Bl, (kl + zo), col0);
        __syncthreads();

        bf16x8_t ah[4], am[4], al[4];
#pragma unroll
        for (int mi = 0; mi < 4; mi++) {
            int r = (wr * 64 + mi * 16 + lm) * 32 + quad * 8;
            ah[mi] = *(const bf16x8_t*)&Ah[r];
            am[mi] = *(const bf16x8_t*)&Am[r];
            al[mi] = *(const bf16x8_t*)&Al[r];
        }
#pragma unroll
        for (int ni = 0; ni < 4; ni++) {
            int rb = (wc * 64 + ni * 16 + lm) * 32 + quad * 8;
            bf16x8_t bh = *(const bf16x8_t*)&Bh[rb];
            bf16x8_t bm = *(const bf16x8_t*)&Bm[rb];
            bf16x8_t bl = *(const bf16x8_t*)&Bl[rb];
#pragma unroll
            for (int mi = 0; mi < 4; mi++)
                MFMA6(acc[mi][ni], ah[mi], am[mi], al[mi], bh, bm, bl);
        }
    }

#pragma unroll
    for (int mi = 0; mi < 4; mi++)
#pragma unroll
        for (int ni = 0; ni < 4; ni++) {
            int row = row0 + wr * 64 + mi * 16 + quad * 4;
            int col = col0 + wc * 64 + ni * 16 + lm;
#pragma unroll
            for (int r = 0; r < 4; r++)
                Cm[(size_t)(row + r) * NN + col] = acc[mi][ni][r] * scale;
        }
}

// ---------------------------------------------------------------------------
// Kernel 3: per (b,n): softmax stats for all 8 channels (no attn writeback),
// channel-summed probs -> top-16, write ml=(max,denom), idx, cnt, countb.
// ---------------------------------------------------------------------------
__global__ __launch_bounds__(256) void softmax_topk(const float* __restrict__ attn,
                                                    float2* __restrict__ ml,
                                                    int* __restrict__ idx,
                                                    int* __restrict__ cnt,
                                                    int* __restrict__ countb) {
    __shared__ float sum[NN];
    __shared__ float wsc[CC][8];
    __shared__ float tv[4];
    __shared__ int ti[4];
    __shared__ int fsel[MAXSEL];
    __shared__ int fcnt;
    const int bn = blockIdx.x, b = bn >> 10, n = bn & 1023;
    const int tid = threadIdx.x, lane = tid & 63, w = tid >> 6;
    const int m4 = tid * 4;

    float4 s4 = make_float4(0.f, 0.f, 0.f, 0.f);
#pragma unroll
    for (int c = 0; c < CC; c++) {
        float4 v = *(const float4*)(attn + (((size_t)(b * CC + c) * NN + n) * NN + m4));
        float mx = fmaxf(fmaxf(v.x, v.y), fmaxf(v.z, v.w));
#pragma unroll
        for (int off = 32; off; off >>= 1) mx = fmaxf(mx, __shfl_down(mx, off));
        if (lane == 0) wsc[c][w] = mx;
        __syncthreads();
        mx = fmaxf(fmaxf(wsc[c][0], wsc[c][1]), fmaxf(wsc[c][2], wsc[c][3]));
        v.x = expf(v.x - mx); v.y = expf(v.y - mx);
        v.z = expf(v.z - mx); v.w = expf(v.w - mx);
        float sm = v.x + v.y + v.z + v.w;
#pragma unroll
        for (int off = 32; off; off >>= 1) sm += __shfl_down(sm, off);
        if (lane == 0) wsc[c][4 + w] = sm;
        __syncthreads();
        float l = wsc[c][4] + wsc[c][5] + wsc[c][6] + wsc[c][7];
        if (tid == 0) ml[(size_t)(b * CC + c) * NN + n] = make_float2(mx, l);
        float inv = 1.0f / l;
        s4.x += v.x * inv; s4.y += v.y * inv; s4.z += v.z * inv; s4.w += v.w * inv;
    }
    *(float4*)&sum[m4] = s4;
    __syncthreads();

    // iterative top-16 (tie-break: lower index, matching jax.lax.top_k)
    for (int it = 0; it < KNBR; it++) {
        float bv = sum[m4]; int bi = m4;
#pragma unroll
        for (int j = 1; j < 4; j++) {
            float x = sum[m4 + j];
            if (x > bv) { bv = x; bi = m4 + j; }
        }
#pragma unroll
        for (int off = 32; off; off >>= 1) {
            float ov = __shfl_down(bv, off);
            int oi = __shfl_down(bi, off);
            if (ov > bv || (ov == bv && oi < bi)) { bv = ov; bi = oi; }
        }
        if (lane == 0) { tv[w] = bv; ti[w] = bi; }
        __syncthreads();
        if (tid == 0) {
            float cv = tv[0]; int ci = ti[0];
#pragma unroll
            for (int k = 1; k < 4; k++)
                if (tv[k] > cv || (tv[k] == cv && ti[k] < ci)) { cv = tv[k]; ci = ti[k]; }
            fsel[it] = ci;
            sum[ci] = -INFINITY;
        }
        __syncthreads();
    }
    if (tid == 0) {
        bool has = false;
        for (int t = 0; t < KNBR; t++)
            if (fsel[t] == n) has = true;
        int c = KNBR;
        if (!has) { fsel[KNBR] = n; c = KNBR + 1; }
        fcnt = c;
        cnt[bn] = c;
    }
    __syncthreads();
    if (tid < fcnt) {
        idx[bn * MAXSEL + tid] = fsel[tid];
        atomicAdd(&countb[b * NN + fsel[tid]], 1);
    }
}

// ---------------------------------------------------------------------------
// Kernel 4: per (z,n) thread: recompute 17 masked probs from raw logits +
// (max,denom); row-normalize; accumulate colsum.
// ---------------------------------------------------------------------------
__global__ __launch_bounds__(256) void rownorm(const float* __restrict__ attn,
                                               const float2* __restrict__ ml,
                                               const int* __restrict__ idx,
                                               const int* __restrict__ cnt,
                                               float* __restrict__ nr,
                                               float* __restrict__ colsum) {
    const int t = blockIdx.x * 256 + threadIdx.x;  // z*N + n
    const int z = t >> 10, n = t & 1023;
    const int b = z >> 3;
    const int bn = b * NN + n;
    const int c_ = cnt[bn];
    const float* arow = attn + (size_t)t * NN;
    const float2 MM = ml[t];
    const float invl = 1.0f / MM.y;
    float a[MAXSEL];
    float s = 0.f;
#pragma unroll
    for (int j = 0; j < MAXSEL; j++) {
        if (j < c_) {
            float p = expf(arow[idx[bn * MAXSEL + j]] - MM.x) * invl;
            a[j] = p; s += p;
        }
    }
    const float inv = 1.f / (s + 1e-6f);
#pragma unroll
    for (int j = 0; j < MAXSEL; j++) {
        if (j < c_) {
            float v = a[j] * inv;
            nr[(size_t)t * MAXSEL + j] = v;
            atomicAdd(&colsum[(size_t)z * NN + idx[bn * MAXSEL + j]], v);
        }
    }
}

// ---------------------------------------------------------------------------
// Kernel 5: per b: exclusive prefix scan of countb[b][0..1023] -> offb.
// ---------------------------------------------------------------------------
__global__ __launch_bounds__(256) void scan_offb(const int* __restrict__ countb,
                                                 int* __restrict__ offb) {
    __shared__ int wtot[4];
    const int b = blockIdx.x, tid = threadIdx.x, lane = tid & 63, w = tid >> 6;
    int c0 = countb[b * NN + tid * 4 + 0];
    int c1 = countb[b * NN + tid * 4 + 1];
    int c2 = countb[b * NN + tid * 4 + 2];
    int c3 = countb[b * NN + tid * 4 + 3];
    int tsum = c0 + c1 + c2 + c3;
    int incl = tsum;
#pragma unroll
    for (int off = 1; off < 64; off <<= 1) {
        int v = __shfl_up(incl, off);
        if (lane >= off) incl += v;
    }
    if (lane == 63) wtot[w] = incl;
    __syncthreads();
    int woff = 0;
    for (int i = 0; i < w; i++) woff += wtot[i];
    int base = woff + incl - tsum;
    offb[b * NN + tid * 4 + 0] = base;
    offb[b * NN + tid * 4 + 1] = base + c0;
    offb[b * NN + tid * 4 + 2] = base + c0 + c1;
    offb[b * NN + tid * 4 + 3] = base + c0 + c1 + c2;
}

// ---------------------------------------------------------------------------
// Kernel 6: init per-z fill cursors from per-b offsets.
// ---------------------------------------------------------------------------
__global__ __launch_bounds__(256) void init_curs(const int* __restrict__ offb,
                                                 int* __restrict__ curs) {
    const int t = blockIdx.x * 256 + threadIdx.x;  // z*N + k
    const int z = t >> 10, k = t & 1023;
    curs[t] = offb[(z >> 3) * NN + k];
}

// ---------------------------------------------------------------------------
// Kernel 7: fill CSR entries: for (z,n,j): k=idx -> append (n, nr/(colsum+eps))
// ---------------------------------------------------------------------------
__global__ __launch_bounds__(256) void fill_csr(const float* __restrict__ nr,
                                                const int* __restrict__ idx,
                                                const int* __restrict__ cnt,
                                                const float* __restrict__ colsum,
                                                int* __restrict__ curs,
                                                int* __restrict__ eidx,
                                                float* __restrict__ eval) {
    const int t = blockIdx.x * 256 + threadIdx.x;  // z*N + n
    const int z = t >> 10, n = t & 1023;
    const int b = z >> 3;
    const int bn = b * NN + n;
    const int c_ = cnt[bn];
    const size_t zb = (size_t)z * ZCAP;
#pragma unroll
    for (int j = 0; j < MAXSEL; j++) {
        if (j < c_) {
            int k = idx[bn * MAXSEL + j];
            float v = nr[(size_t)t * MAXSEL + j] / (colsum[(size_t)z * NN + k] + 1e-6f);
            int p = atomicAdd(&curs[z * NN + k], 1);
            eidx[zb + p] = n;
            eval[zb + p] = v;
        }
    }
}

// ---------------------------------------------------------------------------
// Kernel 8: out[z][n][:] = sum_j w_j * sparse_col(k_j). Block per (z,n):
// scatter ~289 entries into a 4KB LDS row, write dense row once.
// ---------------------------------------------------------------------------
__global__ __launch_bounds__(256) void out_sparse(const float* __restrict__ nr,
                                                  const int* __restrict__ idx,
                                                  const int* __restrict__ cnt,
                                                  const int* __restrict__ offb,
                                                  const int* __restrict__ countb,
                                                  const int* __restrict__ eidx,
                                                  const float* __restrict__ eval,
                                                  float* __restrict__ out) {
    __shared__ float row[NN];
    __shared__ float lw[MAXSEL];
    __shared__ int loff[MAXSEL];
    __shared__ int llen[MAXSEL];
    __shared__ int ps[MAXSEL + 1];
    __shared__ int stot;
    const int t = blockIdx.x;  // z*N + n
    const int z = t >> 10, n = t & 1023;
    const int b = z >> 3;
    const int bn = b * NN + n;
    const int tid = threadIdx.x;
    const size_t zb = (size_t)z * ZCAP;

    ((float4*)row)[tid] = make_float4(0.f, 0.f, 0.f, 0.f);
    const int c_ = cnt[bn];
    if (tid < c_) {
        int k = idx[bn * MAXSEL + tid];
        lw[tid] = nr[(size_t)t * MAXSEL + tid];
        loff[tid] = offb[b * NN + k];
        llen[tid] = countb[b * NN + k];
    }
    __syncthreads();
    if (tid == 0) {
        int acc = 0;
        ps[0] = 0;
        for (int j = 0; j < c_; j++) { acc += llen[j]; ps[j + 1] = acc; }
        stot = acc;
    }
    __syncthreads();
    const int T = stot;
    for (int e = tid; e < T; e += 256) {
        int j = 0;
        while (e >= ps[j + 1]) j++;
        int i = loff[j] + (e - ps[j]);
        float v = eval[zb + i];
        int m = eidx[zb + i];
        atomicAdd(&row[m], lw[j] * v);
    }
    __syncthreads();
    *(float4*)(out + (size_t)t * NN + tid * 4) = ((float4*)row)[tid];
}

// ---------------------------------------------------------------------------
extern "C" void kernel_launch(void* const* d_in, const int* in_sizes, int n_in,
                              void* d_out, int out_size, void* d_ws, size_t ws_size,
                              hipStream_t stream) {
    const float* x = (const float*)d_in[0];    // [4,1024,256]
    const float* W = (const float*)d_in[1];    // [256,4096]
    float* out = (float*)d_out;                // [4,8,1024,1024]
    char* ws = (char*)d_ws;

    // attn (raw logits*scale) lives in d_out; dead before out_sparse writes.
    float* attn = (float*)d_out;

    // workspace layout (bytes)
    __bf16* qh   = (__bf16*)(ws);
    __bf16* qm   = (__bf16*)(ws + 16777216ull);
    __bf16* ql   = (__bf16*)(ws + 33554432ull);
    __bf16* kh   = (__bf16*)(ws + 50331648ull);
    __bf16* km   = (__bf16*)(ws + 67108864ull);
    __bf16* kl   = (__bf16*)(ws + 83886080ull);
    __bf16* xh   = (__bf16*)(ws + 100663296ull);
    __bf16* xm   = (__bf16*)(ws + 102760448ull);
    __bf16* xl   = (__bf16*)(ws + 104857600ull);
    __bf16* wth  = (__bf16*)(ws + 106954752ull);
    __bf16* wtm  = (__bf16*)(ws + 109051904ull);
    __bf16* wtl  = (__bf16*)(ws + 111149056ull);
    int*    idx  = (int*)   (ws + 113246208ull);   // 278,528
    int*    cnt  = (int*)   (ws + 113524736ull);   // 16,384
    float*  nr   = (float*) (ws + 113541120ull);   // 2,228,224
    float*  colsum = (float*)(ws + 115769344ull);  // 131,072
    float2* ml   = (float2*)(ws + 115900416ull);   // 262,144
    int*    countb = (int*) (ws + 116162560ull);   // 16,384
    int*    offb = (int*)   (ws + 116178944ull);   // 16,384
    int*    curs = (int*)   (ws + 116195328ull);   // 131,072
    int*    eidx = (int*)   (ws + 116326400ull);   // 2,228,224
    float*  eval = (float*) (ws + 118554624ull);   // 2,228,224

    split_x<<<1024, 256, 0, stream>>>(x, xh, xm, xl);
    split_wt<<<dim3(64, 4), 256, 0, stream>>>(W, wth, wtm, wtl);
    gemm_xw_mfma<<<dim3(32, 32), 256, 0, stream>>>(xh, xm, xl, wth, wtm, wtl,
                                                   qh, qm, ql, kh, km, kl);
    gemm_qkt_mfma<<<dim3(8, 8, 32), 256, 0, stream>>>(qh, qm, ql, kh, km, kl, attn);
    hipMemsetAsync(colsum, 0, 131072, stream);
    hipMemsetAsync(countb, 0, 16384, stream);
    softmax_topk<<<4096, 256, 0, stream>>>(attn, ml, idx, cnt, countb);
    rownorm<<<128, 256, 0, stream>>>(attn, ml, idx, cnt, nr, colsum);
    scan_offb<<<4, 256, 0, stream>>>(countb, offb);
    init_curs<<<128, 256, 0, stream>>>(offb, curs);
    fill_csr<<<128, 256, 0, stream>>>(nr, idx, cnt, colsum, curs, eidx, eval);
    out_sparse<<<32768, 256, 0, stream>>>(nr, idx, cnt, offb, countb, eidx, eval, out);
}

// Round 5
// 511.068 us; speedup vs baseline: 1.4546x; 1.0310x over previous
//
#include <hip/hip_runtime.h>
#include <hip/hip_bf16.h>
#include <math.h>

// Problem constants
#define BB 4
#define NN 1024
#define DD 256
#define CC 8
#define KNBR 16
#define MAXSEL 17   // 16 top-k + possibly the diagonal
#define ZCAP (NN * MAXSEL)   // 17408 max CSR entries per z

typedef __bf16 bf16x8_t __attribute__((ext_vector_type(8)));
typedef float  f32x4_t  __attribute__((ext_vector_type(4)));

// async global->LDS, 16 bytes per lane. ldsbase must be wave-uniform
// (HW places lane i at ldsbase + i*16).
__device__ __forceinline__ void gl2lds16(const __bf16* g, __bf16* ldsbase) {
    __builtin_amdgcn_global_load_lds(
        (const __attribute__((address_space(1))) unsigned int*)g,
        (__attribute__((address_space(3))) unsigned int*)ldsbase, 16, 0, 0);
}

// 3-level bf16 split: v = h + m + l + eps, |eps| <= 2^-24 |v|
__device__ __forceinline__ void split3(float v, __bf16& h, __bf16& m, __bf16& l) {
    h = (__bf16)v;
    float r = v - (float)h;
    m = (__bf16)r;
    l = (__bf16)(r - (float)m);
}

// ---------------------------------------------------------------------------
// Kernel 0: fused input prep. Blocks 0..1023: split x. Blocks 1024..1279:
// transpose+split W. Block 1024 also zeroes countb.
// ---------------------------------------------------------------------------
__global__ __launch_bounds__(256) void split_all(const float* __restrict__ x,
                                                 const float* __restrict__ W,
                                                 __bf16* __restrict__ xh,
                                                 __bf16* __restrict__ xm,
                                                 __bf16* __restrict__ xl,
                                                 __bf16* __restrict__ Wth,
                                                 __bf16* __restrict__ Wtm,
                                                 __bf16* __restrict__ Wtl,
                                                 int* __restrict__ countb) {
    const int tid = threadIdx.x;
    if (blockIdx.x < 1024) {
        int i = (blockIdx.x * 256 + tid) * 4;
        float4 v = *(const float4*)(x + i);
        __bf16 h0, m0, l0, h1, m1, l1, h2, m2, l2, h3, m3, l3;
        split3(v.x, h0, m0, l0);
        split3(v.y, h1, m1, l1);
        split3(v.z, h2, m2, l2);
        split3(v.w, h3, m3, l3);
        xh[i] = h0; xh[i + 1] = h1; xh[i + 2] = h2; xh[i + 3] = h3;
        xm[i] = m0; xm[i + 1] = m1; xm[i + 2] = m2; xm[i + 3] = m3;
        xl[i] = l0; xl[i + 1] = l1; xl[i + 2] = l2; xl[i + 3] = l3;
    } else {
        const int b2 = blockIdx.x - 1024;
        if (b2 == 0) {
            int4 zz = make_int4(0, 0, 0, 0);
#pragma unroll
            for (int g = 0; g < 4; g++) ((int4*)countb)[tid + 256 * g] = zz;
        }
        __shared__ float t[64][65];
        const int n0 = (b2 & 63) * 64;
        const int k0 = (b2 >> 6) * 64;
#pragma unroll
        for (int i = 0; i < 16; i++) {
            int k = i * 4 + (tid >> 6);
            int n = tid & 63;
            t[k][n] = W[(size_t)(k0 + k) * 4096 + n0 + n];
        }
        __syncthreads();
#pragma unroll
        for (int i = 0; i < 16; i++) {
            int n = i * 4 + (tid >> 6);
            int k = tid & 63;
            __bf16 h, m, l;
            split3(t[k][n], h, m, l);
            size_t o = (size_t)(n0 + n) * 256 + k0 + k;
            Wth[o] = h; Wtm[o] = m; Wtl[o] = l;
        }
    }
}

// stage one 128x32 bf16 tile
#define STAGE1(dst, src, rowbase)                                              \
    do {                                                                       \
        gl2lds16(src + (size_t)((rowbase) + r_st) * 256 + k0 + c8,             \
                 &dst[(w * 64) * 8]);                                          \
        gl2lds16(src + (size_t)((rowbase) + 64 + r_st) * 256 + k0 + c8,        \
                 &dst[(256 + w * 64) * 8]);                                    \
    } while (0)

// 6-term product ladder, smallest first (hh last)
#define MFMA6(accv, AH, AM, AL, BH, BM, BL)                                    \
    do {                                                                       \
        accv = __builtin_amdgcn_mfma_f32_16x16x32_bf16(AL, BH, accv, 0, 0, 0); \
        accv = __builtin_amdgcn_mfma_f32_16x16x32_bf16(AH, BL, accv, 0, 0, 0); \
        accv = __builtin_amdgcn_mfma_f32_16x16x32_bf16(AM, BM, accv, 0, 0, 0); \
        accv = __builtin_amdgcn_mfma_f32_16x16x32_bf16(AM, BH, accv, 0, 0, 0); \
        accv = __builtin_amdgcn_mfma_f32_16x16x32_bf16(AH, BM, accv, 0, 0, 0); \
        accv = __builtin_amdgcn_mfma_f32_16x16x32_bf16(AH, BH, accv, 0, 0, 0); \
    } while (0)

// ---------------------------------------------------------------------------
// Kernel 1: qk = x @ W via 6-term bf16x3 MFMA; LDS-transpose epilogue with
// coalesced bf16x8 stores of the 3-split q/k components.
// ---------------------------------------------------------------------------
__global__ __launch_bounds__(256) void gemm_xw_mfma(
        const __bf16* __restrict__ xh, const __bf16* __restrict__ xm,
        const __bf16* __restrict__ xl, const __bf16* __restrict__ wth,
        const __bf16* __restrict__ wtm, const __bf16* __restrict__ wtl,
        __bf16* __restrict__ qh, __bf16* __restrict__ qm, __bf16* __restrict__ ql,
        __bf16* __restrict__ kh, __bf16* __restrict__ km, __bf16* __restrict__ kl) {
    __shared__ __align__(16) char smem[49152];
    __bf16* Ah = (__bf16*)smem;
    __bf16* Am = Ah + 4096;
    __bf16* Al = Am + 4096;
    __bf16* Bh = Al + 4096;
    __bf16* Bm = Bh + 4096;
    __bf16* Bl = Bm + 4096;
    const int tid = threadIdx.x, lane = tid & 63, w = tid >> 6;
    const int wr = w >> 1, wc = w & 1;
    const int lm = lane & 15, quad = lane >> 4;
    const int row0 = blockIdx.y * 128, col0 = blockIdx.x * 128;
    const int r_st = tid >> 2;
    const int c8 = (tid & 3) * 8;

    f32x4_t acc[4][4];
#pragma unroll
    for (int i = 0; i < 4; i++)
#pragma unroll
        for (int j = 0; j < 4; j++) acc[i][j] = (f32x4_t)(0.f);

    for (int k0 = 0; k0 < 256; k0 += 32) {
        __syncthreads();
        STAGE1(Ah, xh, row0); STAGE1(Am, xm, row0); STAGE1(Al, xl, row0);
        STAGE1(Bh, wth, col0); STAGE1(Bm, wtm, col0); STAGE1(Bl, wtl, col0);
        __syncthreads();

        bf16x8_t ah[4], am[4], al[4];
#pragma unroll
        for (int mi = 0; mi < 4; mi++) {
            int r = (wr * 64 + mi * 16 + lm) * 32 + quad * 8;
            ah[mi] = *(const bf16x8_t*)&Ah[r];
            am[mi] = *(const bf16x8_t*)&Am[r];
            al[mi] = *(const bf16x8_t*)&Al[r];
        }
#pragma unroll
        for (int ni = 0; ni < 4; ni++) {
            int rb = (wc * 64 + ni * 16 + lm) * 32 + quad * 8;
            bf16x8_t bh = *(const bf16x8_t*)&Bh[rb];
            bf16x8_t bm = *(const bf16x8_t*)&Bm[rb];
            bf16x8_t bl = *(const bf16x8_t*)&Bl[rb];
#pragma unroll
            for (int mi = 0; mi < 4; mi++)
                MFMA6(acc[mi][ni], ah[mi], am[mi], al[mi], bh, bm, bl);
        }
    }

    // Epilogue: two 64-row passes through LDS (fp32, stride 132 = bank-safe),
    // then coalesced bf16x8 stores of the 3 split components.
    __syncthreads();
    float* tr = (float*)smem;   // 64 x 132 fp32 = 33792 B
    const int s = col0 >> 11, c = (col0 >> 8) & 7, dbase = col0 & 255;
    __bf16* dh = s ? kh : qh;
    __bf16* dm = s ? km : qm;
    __bf16* dl = s ? kl : ql;
    const int rl = tid >> 2;
    const int cb = (tid & 3) * 8;
#pragma unroll
    for (int p = 0; p < 2; p++) {
        if (p) __syncthreads();
        if (wr == p) {
#pragma unroll
            for (int mi = 0; mi < 4; mi++) {
                int rloc = mi * 16 + quad * 4;
#pragma unroll
                for (int ni = 0; ni < 4; ni++) {
                    int cl = wc * 64 + ni * 16 + lm;
#pragma unroll
                    for (int r = 0; r < 4; r++)
                        tr[(rloc + r) * 132 + cl] = acc[mi][ni][r];
                }
            }
        }
        __syncthreads();
        int rr = row0 + p * 64 + rl;
        int bb = rr >> 10, n = rr & 1023;
        size_t base = (((size_t)(bb * CC + c)) * NN + n) * DD + dbase;
#pragma unroll
        for (int g = 0; g < 4; g++) {
            int ccol = g * 32 + cb;
            bf16x8_t hv, mv, lv;
#pragma unroll
            for (int e = 0; e < 8; e++) {
                float vv = tr[rl * 132 + ccol + e];
                __bf16 h, m, l;
                split3(vv, h, m, l);
                hv[e] = h; mv[e] = m; lv[e] = l;
            }
            *(bf16x8_t*)(dh + base + ccol) = hv;
            *(bf16x8_t*)(dm + base + ccol) = mv;
            *(bf16x8_t*)(dl + base + ccol) = lv;
        }
    }
}

// ---------------------------------------------------------------------------
// Kernel 2: per z: attn = (q @ k^T) * scale via 6-term bf16x3 MFMA.
// 1D grid of 2048, swizzled so all 64 blocks of a z share one XCD (id%8).
// ---------------------------------------------------------------------------
__global__ __launch_bounds__(256) void gemm_qkt_mfma(
        const __bf16* __restrict__ qh, const __bf16* __restrict__ qm,
        const __bf16* __restrict__ ql, const __bf16* __restrict__ kh,
        const __bf16* __restrict__ km, const __bf16* __restrict__ kl,
        float* __restrict__ attn) {
    __shared__ __bf16 Ah[128 * 32], Am[128 * 32], Al[128 * 32];
    __shared__ __bf16 Bh[128 * 32], Bm[128 * 32], Bl[128 * 32];
    const int tid = threadIdx.x, lane = tid & 63, w = tid >> 6;
    const int wr = w >> 1, wc = w & 1;
    const int lm = lane & 15, quad = lane >> 4;
    // XCD swizzle: id%8 selects XCD; give each z its own residue class.
    const int id = blockIdx.x;
    const int rb8 = id & 7, qq = id >> 3;
    const int j = qq & 63, zhi = qq >> 6;
    const int z = zhi * 8 + rb8;
    const int row0 = (j >> 3) * 128, col0 = (j & 7) * 128;
    const size_t zo = (size_t)z * NN * DD;
    float* Cm = attn + (size_t)z * NN * NN;
    const int r_st = tid >> 2;
    const int c8 = (tid & 3) * 8;
    const float scale = 0.0625f;

    f32x4_t acc[4][4];
#pragma unroll
    for (int i = 0; i < 4; i++)
#pragma unroll
        for (int j2 = 0; j2 < 4; j2++) acc[i][j2] = (f32x4_t)(0.f);

    for (int k0 = 0; k0 < 256; k0 += 32) {
        __syncthreads();
        STAGE1(Ah, (qh + zo), row0); STAGE1(Am, (qm + zo), row0); STAGE1(Al, (ql + zo), row0);
        STAGE1(Bh, (kh + zo), col0); STAGE1(Bm, (km + zo), col0); STAGE1(Bl, (kl + zo), col0);
        __syncthreads();

        bf16x8_t ah[4], am[4], al[4];
#pragma unroll
        for (int mi = 0; mi < 4; mi++) {
            int r = (wr * 64 + mi * 16 + lm) * 32 + quad * 8;
            ah[mi] = *(const bf16x8_t*)&Ah[r];
            am[mi] = *(const bf16x8_t*)&Am[r];
            al[mi] = *(const bf16x8_t*)&Al[r];
        }
#pragma unroll
        for (int ni = 0; ni < 4; ni++) {
            int rbb = (wc * 64 + ni * 16 + lm) * 32 + quad * 8;
            bf16x8_t bh = *(const bf16x8_t*)&Bh[rbb];
            bf16x8_t bm = *(const bf16x8_t*)&Bm[rbb];
            bf16x8_t bl = *(const bf16x8_t*)&Bl[rbb];
#pragma unroll
            for (int mi = 0; mi < 4; mi++)
                MFMA6(acc[mi][ni], ah[mi], am[mi], al[mi], bh, bm, bl);
        }
    }

#pragma unroll
    for (int mi = 0; mi < 4; mi++)
#pragma unroll
        for (int ni = 0; ni < 4; ni++) {
            int row = row0 + wr * 64 + mi * 16 + quad * 4;
            int col = col0 + wc * 64 + ni * 16 + lm;
#pragma unroll
            for (int r = 0; r < 4; r++)
                Cm[(size_t)(row + r) * NN + col] = acc[mi][ni][r] * scale;
        }
}

// ---------------------------------------------------------------------------
// Kernel 3: per (b,n): softmax stats for all 8 channels (no attn writeback),
// channel-summed probs -> top-16; writes ml, idx, cnt, countb; zeroes colsum.
// ---------------------------------------------------------------------------
__global__ __launch_bounds__(256) void softmax_topk(const float* __restrict__ attn,
                                                    float2* __restrict__ ml,
                                                    int* __restrict__ idx,
                                                    int* __restrict__ cnt,
                                                    int* __restrict__ countb,
                                                    float* __restrict__ colsum) {
    __shared__ float sum[NN];
    __shared__ float wsc[CC][8];
    __shared__ float tv[4];
    __shared__ int ti[4];
    __shared__ int fsel[MAXSEL];
    __shared__ int fcnt;
    const int bn = blockIdx.x, b = bn >> 10, n = bn & 1023;
    const int tid = threadIdx.x, lane = tid & 63, w = tid >> 6;
    const int m4 = tid * 4;

    // zero colsum (read only by the later rownorm kernel)
    if (tid < CC) colsum[(size_t)(b * CC + tid) * NN + n] = 0.f;

    float4 s4 = make_float4(0.f, 0.f, 0.f, 0.f);
#pragma unroll
    for (int c = 0; c < CC; c++) {
        float4 v = *(const float4*)(attn + (((size_t)(b * CC + c) * NN + n) * NN + m4));
        float mx = fmaxf(fmaxf(v.x, v.y), fmaxf(v.z, v.w));
#pragma unroll
        for (int off = 32; off; off >>= 1) mx = fmaxf(mx, __shfl_down(mx, off));
        if (lane == 0) wsc[c][w] = mx;
        __syncthreads();
        mx = fmaxf(fmaxf(wsc[c][0], wsc[c][1]), fmaxf(wsc[c][2], wsc[c][3]));
        v.x = expf(v.x - mx); v.y = expf(v.y - mx);
        v.z = expf(v.z - mx); v.w = expf(v.w - mx);
        float sm = v.x + v.y + v.z + v.w;
#pragma unroll
        for (int off = 32; off; off >>= 1) sm += __shfl_down(sm, off);
        if (lane == 0) wsc[c][4 + w] = sm;
        __syncthreads();
        float l = wsc[c][4] + wsc[c][5] + wsc[c][6] + wsc[c][7];
        if (tid == 0) ml[(size_t)(b * CC + c) * NN + n] = make_float2(mx, l);
        float inv = 1.0f / l;
        s4.x += v.x * inv; s4.y += v.y * inv; s4.z += v.z * inv; s4.w += v.w * inv;
    }
    *(float4*)&sum[m4] = s4;
    __syncthreads();

    // iterative top-16 (tie-break: lower index, matching jax.lax.top_k)
    for (int it = 0; it < KNBR; it++) {
        float bv = sum[m4]; int bi = m4;
#pragma unroll
        for (int j = 1; j < 4; j++) {
            float x = sum[m4 + j];
            if (x > bv) { bv = x; bi = m4 + j; }
        }
#pragma unroll
        for (int off = 32; off; off >>= 1) {
            float ov = __shfl_down(bv, off);
            int oi = __shfl_down(bi, off);
            if (ov > bv || (ov == bv && oi < bi)) { bv = ov; bi = oi; }
        }
        if (lane == 0) { tv[w] = bv; ti[w] = bi; }
        __syncthreads();
        if (tid == 0) {
            float cv = tv[0]; int ci = ti[0];
#pragma unroll
            for (int k = 1; k < 4; k++)
                if (tv[k] > cv || (tv[k] == cv && ti[k] < ci)) { cv = tv[k]; ci = ti[k]; }
            fsel[it] = ci;
            sum[ci] = -INFINITY;
        }
        __syncthreads();
    }
    if (tid == 0) {
        bool has = false;
        for (int t = 0; t < KNBR; t++)
            if (fsel[t] == n) has = true;
        int c = KNBR;
        if (!has) { fsel[KNBR] = n; c = KNBR + 1; }
        fcnt = c;
        cnt[bn] = c;
    }
    __syncthreads();
    if (tid < fcnt) {
        idx[bn * MAXSEL + tid] = fsel[tid];
        atomicAdd(&countb[b * NN + fsel[tid]], 1);
    }
}

// ---------------------------------------------------------------------------
// Kernel 4: per (z,n) thread: recompute 17 masked probs from raw logits +
// (max,denom); row-normalize; accumulate colsum.
// ---------------------------------------------------------------------------
__global__ __launch_bounds__(256) void rownorm(const float* __restrict__ attn,
                                               const float2* __restrict__ ml,
                                               const int* __restrict__ idx,
                                               const int* __restrict__ cnt,
                                               float* __restrict__ nr,
                                               float* __restrict__ colsum) {
    const int t = blockIdx.x * 256 + threadIdx.x;  // z*N + n
    const int z = t >> 10, n = t & 1023;
    const int b = z >> 3;
    const int bn = b * NN + n;
    const int c_ = cnt[bn];
    const float* arow = attn + (size_t)t * NN;
    const float2 MM = ml[t];
    const float invl = 1.0f / MM.y;
    float a[MAXSEL];
    float s = 0.f;
#pragma unroll
    for (int j = 0; j < MAXSEL; j++) {
        if (j < c_) {
            float p = expf(arow[idx[bn * MAXSEL + j]] - MM.x) * invl;
            a[j] = p; s += p;
        }
    }
    const float inv = 1.f / (s + 1e-6f);
#pragma unroll
    for (int j = 0; j < MAXSEL; j++) {
        if (j < c_) {
            float v = a[j] * inv;
            nr[(size_t)t * MAXSEL + j] = v;
            atomicAdd(&colsum[(size_t)z * NN + idx[bn * MAXSEL + j]], v);
        }
    }
}

// ---------------------------------------------------------------------------
// Kernel 5: per b: exclusive prefix scan of countb -> offb; init curs for
// the 8 z's of this b.
// ---------------------------------------------------------------------------
__global__ __launch_bounds__(256) void scan_offb(const int* __restrict__ countb,
                                                 int* __restrict__ offb,
                                                 int* __restrict__ curs) {
    __shared__ int wtot[4];
    const int b = blockIdx.x, tid = threadIdx.x, lane = tid & 63, w = tid >> 6;
    int c0 = countb[b * NN + tid * 4 + 0];
    int c1 = countb[b * NN + tid * 4 + 1];
    int c2 = countb[b * NN + tid * 4 + 2];
    int c3 = countb[b * NN + tid * 4 + 3];
    int tsum = c0 + c1 + c2 + c3;
    int incl = tsum;
#pragma unroll
    for (int off = 1; off < 64; off <<= 1) {
        int v = __shfl_up(incl, off);
        if (lane >= off) incl += v;
    }
    if (lane == 63) wtot[w] = incl;
    __syncthreads();
    int woff = 0;
    for (int i = 0; i < w; i++) woff += wtot[i];
    int base = woff + incl - tsum;
    int o0 = base, o1 = base + c0, o2 = base + c0 + c1, o3 = base + c0 + c1 + c2;
    offb[b * NN + tid * 4 + 0] = o0;
    offb[b * NN + tid * 4 + 1] = o1;
    offb[b * NN + tid * 4 + 2] = o2;
    offb[b * NN + tid * 4 + 3] = o3;
#pragma unroll
    for (int c = 0; c < CC; c++) {
        int z = b * CC + c;
        curs[z * NN + tid * 4 + 0] = o0;
        curs[z * NN + tid * 4 + 1] = o1;
        curs[z * NN + tid * 4 + 2] = o2;
        curs[z * NN + tid * 4 + 3] = o3;
    }
}

// ---------------------------------------------------------------------------
// Kernel 6: fill CSR entries: for (z,n,j): k=idx -> append (n, nr/(colsum+eps))
// ---------------------------------------------------------------------------
__global__ __launch_bounds__(256) void fill_csr(const float* __restrict__ nr,
                                                const int* __restrict__ idx,
                                                const int* __restrict__ cnt,
                                                const float* __restrict__ colsum,
                                                int* __restrict__ curs,
                                                int* __restrict__ eidx,
                                                float* __restrict__ eval) {
    const int t = blockIdx.x * 256 + threadIdx.x;  // z*N + n
    const int z = t >> 10, n = t & 1023;
    const int b = z >> 3;
    const int bn = b * NN + n;
    const int c_ = cnt[bn];
    const size_t zb = (size_t)z * ZCAP;
#pragma unroll
    for (int j = 0; j < MAXSEL; j++) {
        if (j < c_) {
            int k = idx[bn * MAXSEL + j];
            float v = nr[(size_t)t * MAXSEL + j] / (colsum[(size_t)z * NN + k] + 1e-6f);
            int p = atomicAdd(&curs[z * NN + k], 1);
            eidx[zb + p] = n;
            eval[zb + p] = v;
        }
    }
}

// ---------------------------------------------------------------------------
// Kernel 7: out[z][n][:] = sum_j w_j * sparse_col(k_j). Block per (z,n):
// scatter ~289 entries into a 4KB LDS row, write dense row once.
// ---------------------------------------------------------------------------
__global__ __launch_bounds__(256) void out_sparse(const float* __restrict__ nr,
                                                  const int* __restrict__ idx,
                                                  const int* __restrict__ cnt,
                                                  const int* __restrict__ offb,
                                                  const int* __restrict__ countb,
                                                  const int* __restrict__ eidx,
                                                  const float* __restrict__ eval,
                                                  float* __restrict__ out) {
    __shared__ float row[NN];
    __shared__ float lw[MAXSEL];
    __shared__ int loff[MAXSEL];
    __shared__ int llen[MAXSEL];
    __shared__ int ps[MAXSEL + 1];
    __shared__ int stot;
    const int t = blockIdx.x;  // z*N + n
    const int z = t >> 10, n = t & 1023;
    const int b = z >> 3;
    const int bn = b * NN + n;
    const int tid = threadIdx.x;
    const size_t zb = (size_t)z * ZCAP;

    ((float4*)row)[tid] = make_float4(0.f, 0.f, 0.f, 0.f);
    const int c_ = cnt[bn];
    if (tid < c_) {
        int k = idx[bn * MAXSEL + tid];
        lw[tid] = nr[(size_t)t * MAXSEL + tid];
        loff[tid] = offb[b * NN + k];
        llen[tid] = countb[b * NN + k];
    }
    __syncthreads();
    if (tid == 0) {
        int acc = 0;
        ps[0] = 0;
        for (int j = 0; j < c_; j++) { acc += llen[j]; ps[j + 1] = acc; }
        stot = acc;
    }
    __syncthreads();
    const int T = stot;
    for (int e = tid; e < T; e += 256) {
        int j = 0;
        while (e >= ps[j + 1]) j++;
        int i = loff[j] + (e - ps[j]);
        float v = eval[zb + i];
        int m = eidx[zb + i];
        atomicAdd(&row[m], lw[j] * v);
    }
    __syncthreads();
    *(float4*)(out + (size_t)t * NN + tid * 4) = ((float4*)row)[tid];
}

// ---------------------------------------------------------------------------
extern "C" void kernel_launch(void* const* d_in, const int* in_sizes, int n_in,
                              void* d_out, int out_size, void* d_ws, size_t ws_size,
                              hipStream_t stream) {
    const float* x = (const float*)d_in[0];    // [4,1024,256]
    const float* W = (const float*)d_in[1];    // [256,4096]
    float* out = (float*)d_out;                // [4,8,1024,1024]
    char* ws = (char*)d_ws;

    // attn (raw logits*scale) lives in d_out; dead before out_sparse writes.
    float* attn = (float*)d_out;

    // workspace layout (bytes)
    __bf16* qh   = (__bf16*)(ws);
    __bf16* qm   = (__bf16*)(ws + 16777216ull);
    __bf16* ql   = (__bf16*)(ws + 33554432ull);
    __bf16* kh   = (__bf16*)(ws + 50331648ull);
    __bf16* km   = (__bf16*)(ws + 67108864ull);
    __bf16* kl   = (__bf16*)(ws + 83886080ull);
    __bf16* xh   = (__bf16*)(ws + 100663296ull);
    __bf16* xm   = (__bf16*)(ws + 102760448ull);
    __bf16* xl   = (__bf16*)(ws + 104857600ull);
    __bf16* wth  = (__bf16*)(ws + 106954752ull);
    __bf16* wtm  = (__bf16*)(ws + 109051904ull);
    __bf16* wtl  = (__bf16*)(ws + 111149056ull);
    int*    idx  = (int*)   (ws + 113246208ull);   // 278,528
    int*    cnt  = (int*)   (ws + 113524736ull);   // 16,384
    float*  nr   = (float*) (ws + 113541120ull);   // 2,228,224
    float*  colsum = (float*)(ws + 115769344ull);  // 131,072
    float2* ml   = (float2*)(ws + 115900416ull);   // 262,144
    int*    countb = (int*) (ws + 116162560ull);   // 16,384
    int*    offb = (int*)   (ws + 116178944ull);   // 16,384
    int*    curs = (int*)   (ws + 116195328ull);   // 131,072
    int*    eidx = (int*)   (ws + 116326400ull);   // 2,228,224
    float*  eval = (float*) (ws + 118554624ull);   // 2,228,224

    split_all<<<1280, 256, 0, stream>>>(x, W, xh, xm, xl, wth, wtm, wtl, countb);
    gemm_xw_mfma<<<dim3(32, 32), 256, 0, stream>>>(xh, xm, xl, wth, wtm, wtl,
                                                   qh, qm, ql, kh, km, kl);
    gemm_qkt_mfma<<<2048, 256, 0, stream>>>(qh, qm, ql, kh, km, kl, attn);
    softmax_topk<<<4096, 256, 0, stream>>>(attn, ml, idx, cnt, countb, colsum);
    rownorm<<<128, 256, 0, stream>>>(attn, ml, idx, cnt, nr, colsum);
    scan_offb<<<4, 256, 0, stream>>>(countb, offb, curs);
    fill_csr<<<128, 256, 0, stream>>>(nr, idx, cnt, colsum, curs, eidx, eval);
    out_sparse<<<32768, 256, 0, stream>>>(nr, idx, cnt, offb, countb, eidx, eval, out);
}

// Round 6
// 470.570 us; speedup vs baseline: 1.5798x; 1.0861x over previous
//
#include <hip/hip_runtime.h>
#include <hip/hip_bf16.h>
#include <math.h>

// Problem constants
#define BB 4
#define NN 1024
#define DD 256
#define CC 8
#define KNBR 16
#define MAXSEL 17   // 16 top-k + possibly the diagonal
#define ZCAP (NN * MAXSEL)   // 17408 max CSR entries per z

typedef __bf16 bf16x8_t __attribute__((ext_vector_type(8)));
typedef float  f32x4_t  __attribute__((ext_vector_type(4)));

// async global->LDS, 16 bytes per lane. ldsbase must be wave-uniform
// (HW places lane i at ldsbase + i*16).
__device__ __forceinline__ void gl2lds16(const __bf16* g, __bf16* ldsbase) {
    __builtin_amdgcn_global_load_lds(
        (const __attribute__((address_space(1))) unsigned int*)g,
        (__attribute__((address_space(3))) unsigned int*)ldsbase, 16, 0, 0);
}

// 3-level bf16 split: v = h + m + l + eps, |eps| <= 2^-24 |v|
__device__ __forceinline__ void split3(float v, __bf16& h, __bf16& m, __bf16& l) {
    h = (__bf16)v;
    float r = v - (float)h;
    m = (__bf16)r;
    l = (__bf16)(r - (float)m);
}

// ---------------------------------------------------------------------------
// Kernel 0: fused input prep. Blocks 0..1023: split x. Blocks 1024..1279:
// transpose+split W. Block 1024 also zeroes countb.
// ---------------------------------------------------------------------------
__global__ __launch_bounds__(256) void split_all(const float* __restrict__ x,
                                                 const float* __restrict__ W,
                                                 __bf16* __restrict__ xh,
                                                 __bf16* __restrict__ xm,
                                                 __bf16* __restrict__ xl,
                                                 __bf16* __restrict__ Wth,
                                                 __bf16* __restrict__ Wtm,
                                                 __bf16* __restrict__ Wtl,
                                                 int* __restrict__ countb) {
    const int tid = threadIdx.x;
    if (blockIdx.x < 1024) {
        int i = (blockIdx.x * 256 + tid) * 4;
        float4 v = *(const float4*)(x + i);
        __bf16 h0, m0, l0, h1, m1, l1, h2, m2, l2, h3, m3, l3;
        split3(v.x, h0, m0, l0);
        split3(v.y, h1, m1, l1);
        split3(v.z, h2, m2, l2);
        split3(v.w, h3, m3, l3);
        xh[i] = h0; xh[i + 1] = h1; xh[i + 2] = h2; xh[i + 3] = h3;
        xm[i] = m0; xm[i + 1] = m1; xm[i + 2] = m2; xm[i + 3] = m3;
        xl[i] = l0; xl[i + 1] = l1; xl[i + 2] = l2; xl[i + 3] = l3;
    } else {
        const int b2 = blockIdx.x - 1024;
        if (b2 == 0) {
            int4 zz = make_int4(0, 0, 0, 0);
#pragma unroll
            for (int g = 0; g < 4; g++) ((int4*)countb)[tid + 256 * g] = zz;
        }
        __shared__ float t[64][65];
        const int n0 = (b2 & 63) * 64;
        const int k0 = (b2 >> 6) * 64;
#pragma unroll
        for (int i = 0; i < 16; i++) {
            int k = i * 4 + (tid >> 6);
            int n = tid & 63;
            t[k][n] = W[(size_t)(k0 + k) * 4096 + n0 + n];
        }
        __syncthreads();
#pragma unroll
        for (int i = 0; i < 16; i++) {
            int n = i * 4 + (tid >> 6);
            int k = tid & 63;
            __bf16 h, m, l;
            split3(t[k][n], h, m, l);
            size_t o = (size_t)(n0 + n) * 256 + k0 + k;
            Wth[o] = h; Wtm[o] = m; Wtl[o] = l;
        }
    }
}

// stage one 128x32 bf16 tile
#define STAGE1(dst, src, rowbase)                                              \
    do {                                                                       \
        gl2lds16(src + (size_t)((rowbase) + r_st) * 256 + k0 + c8,             \
                 &dst[(w * 64) * 8]);                                          \
        gl2lds16(src + (size_t)((rowbase) + 64 + r_st) * 256 + k0 + c8,        \
                 &dst[(256 + w * 64) * 8]);                                    \
    } while (0)

// 6-term product ladder, smallest first (hh last)
#define MFMA6(accv, AH, AM, AL, BH, BM, BL)                                    \
    do {                                                                       \
        accv = __builtin_amdgcn_mfma_f32_16x16x32_bf16(AL, BH, accv, 0, 0, 0); \
        accv = __builtin_amdgcn_mfma_f32_16x16x32_bf16(AH, BL, accv, 0, 0, 0); \
        accv = __builtin_amdgcn_mfma_f32_16x16x32_bf16(AM, BM, accv, 0, 0, 0); \
        accv = __builtin_amdgcn_mfma_f32_16x16x32_bf16(AM, BH, accv, 0, 0, 0); \
        accv = __builtin_amdgcn_mfma_f32_16x16x32_bf16(AH, BM, accv, 0, 0, 0); \
        accv = __builtin_amdgcn_mfma_f32_16x16x32_bf16(AH, BH, accv, 0, 0, 0); \
    } while (0)

// ---------------------------------------------------------------------------
// Kernel 1: qk = x @ W via 6-term bf16x3 MFMA; LDS-transpose epilogue with
// coalesced bf16x8 stores of the 3-split q/k components.
// ---------------------------------------------------------------------------
__global__ __launch_bounds__(256) void gemm_xw_mfma(
        const __bf16* __restrict__ xh, const __bf16* __restrict__ xm,
        const __bf16* __restrict__ xl, const __bf16* __restrict__ wth,
        const __bf16* __restrict__ wtm, const __bf16* __restrict__ wtl,
        __bf16* __restrict__ qh, __bf16* __restrict__ qm, __bf16* __restrict__ ql,
        __bf16* __restrict__ kh, __bf16* __restrict__ km, __bf16* __restrict__ kl) {
    __shared__ __align__(16) char smem[49152];
    __bf16* Ah = (__bf16*)smem;
    __bf16* Am = Ah + 4096;
    __bf16* Al = Am + 4096;
    __bf16* Bh = Al + 4096;
    __bf16* Bm = Bh + 4096;
    __bf16* Bl = Bm + 4096;
    const int tid = threadIdx.x, lane = tid & 63, w = tid >> 6;
    const int wr = w >> 1, wc = w & 1;
    const int lm = lane & 15, quad = lane >> 4;
    const int row0 = blockIdx.y * 128, col0 = blockIdx.x * 128;
    const int r_st = tid >> 2;
    const int c8 = (tid & 3) * 8;

    f32x4_t acc[4][4];
#pragma unroll
    for (int i = 0; i < 4; i++)
#pragma unroll
        for (int j = 0; j < 4; j++) acc[i][j] = (f32x4_t)(0.f);

    for (int k0 = 0; k0 < 256; k0 += 32) {
        __syncthreads();
        STAGE1(Ah, xh, row0); STAGE1(Am, xm, row0); STAGE1(Al, xl, row0);
        STAGE1(Bh, wth, col0); STAGE1(Bm, wtm, col0); STAGE1(Bl, wtl, col0);
        __syncthreads();

        bf16x8_t ah[4], am[4], al[4];
#pragma unroll
        for (int mi = 0; mi < 4; mi++) {
            int r = (wr * 64 + mi * 16 + lm) * 32 + quad * 8;
            ah[mi] = *(const bf16x8_t*)&Ah[r];
            am[mi] = *(const bf16x8_t*)&Am[r];
            al[mi] = *(const bf16x8_t*)&Al[r];
        }
#pragma unroll
        for (int ni = 0; ni < 4; ni++) {
            int rb = (wc * 64 + ni * 16 + lm) * 32 + quad * 8;
            bf16x8_t bh = *(const bf16x8_t*)&Bh[rb];
            bf16x8_t bm = *(const bf16x8_t*)&Bm[rb];
            bf16x8_t bl = *(const bf16x8_t*)&Bl[rb];
#pragma unroll
            for (int mi = 0; mi < 4; mi++)
                MFMA6(acc[mi][ni], ah[mi], am[mi], al[mi], bh, bm, bl);
        }
    }

    // Epilogue: two 64-row passes through LDS (fp32, stride 132 = bank-safe),
    // then coalesced bf16x8 stores of the 3 split components.
    __syncthreads();
    float* tr = (float*)smem;   // 64 x 132 fp32 = 33792 B
    const int s = col0 >> 11, c = (col0 >> 8) & 7, dbase = col0 & 255;
    __bf16* dh = s ? kh : qh;
    __bf16* dm = s ? km : qm;
    __bf16* dl = s ? kl : ql;
    const int rl = tid >> 2;
    const int cb = (tid & 3) * 8;
#pragma unroll
    for (int p = 0; p < 2; p++) {
        if (p) __syncthreads();
        if (wr == p) {
#pragma unroll
            for (int mi = 0; mi < 4; mi++) {
                int rloc = mi * 16 + quad * 4;
#pragma unroll
                for (int ni = 0; ni < 4; ni++) {
                    int cl = wc * 64 + ni * 16 + lm;
#pragma unroll
                    for (int r = 0; r < 4; r++)
                        tr[(rloc + r) * 132 + cl] = acc[mi][ni][r];
                }
            }
        }
        __syncthreads();
        int rr = row0 + p * 64 + rl;
        int bb = rr >> 10, n = rr & 1023;
        size_t base = (((size_t)(bb * CC + c)) * NN + n) * DD + dbase;
#pragma unroll
        for (int g = 0; g < 4; g++) {
            int ccol = g * 32 + cb;
            bf16x8_t hv, mv, lv;
#pragma unroll
            for (int e = 0; e < 8; e++) {
                float vv = tr[rl * 132 + ccol + e];
                __bf16 h, m, l;
                split3(vv, h, m, l);
                hv[e] = h; mv[e] = m; lv[e] = l;
            }
            *(bf16x8_t*)(dh + base + ccol) = hv;
            *(bf16x8_t*)(dm + base + ccol) = mv;
            *(bf16x8_t*)(dl + base + ccol) = lv;
        }
    }
}

// ---------------------------------------------------------------------------
// Kernel 2: per z: attn = (q @ k^T) * scale via 6-term bf16x3 MFMA.
// 1D grid of 2048, swizzled so all 64 blocks of a z share one XCD (id%8).
// ---------------------------------------------------------------------------
__global__ __launch_bounds__(256) void gemm_qkt_mfma(
        const __bf16* __restrict__ qh, const __bf16* __restrict__ qm,
        const __bf16* __restrict__ ql, const __bf16* __restrict__ kh,
        const __bf16* __restrict__ km, const __bf16* __restrict__ kl,
        float* __restrict__ attn) {
    __shared__ __bf16 Ah[128 * 32], Am[128 * 32], Al[128 * 32];
    __shared__ __bf16 Bh[128 * 32], Bm[128 * 32], Bl[128 * 32];
    const int tid = threadIdx.x, lane = tid & 63, w = tid >> 6;
    const int wr = w >> 1, wc = w & 1;
    const int lm = lane & 15, quad = lane >> 4;
    const int id = blockIdx.x;
    const int rb8 = id & 7, qq = id >> 3;
    const int j = qq & 63, zhi = qq >> 6;
    const int z = zhi * 8 + rb8;
    const int row0 = (j >> 3) * 128, col0 = (j & 7) * 128;
    const size_t zo = (size_t)z * NN * DD;
    float* Cm = attn + (size_t)z * NN * NN;
    const int r_st = tid >> 2;
    const int c8 = (tid & 3) * 8;
    const float scale = 0.0625f;

    f32x4_t acc[4][4];
#pragma unroll
    for (int i = 0; i < 4; i++)
#pragma unroll
        for (int j2 = 0; j2 < 4; j2++) acc[i][j2] = (f32x4_t)(0.f);

    for (int k0 = 0; k0 < 256; k0 += 32) {
        __syncthreads();
        STAGE1(Ah, (qh + zo), row0); STAGE1(Am, (qm + zo), row0); STAGE1(Al, (ql + zo), row0);
        STAGE1(Bh, (kh + zo), col0); STAGE1(Bm, (km + zo), col0); STAGE1(Bl, (kl + zo), col0);
        __syncthreads();

        bf16x8_t ah[4], am[4], al[4];
#pragma unroll
        for (int mi = 0; mi < 4; mi++) {
            int r = (wr * 64 + mi * 16 + lm) * 32 + quad * 8;
            ah[mi] = *(const bf16x8_t*)&Ah[r];
            am[mi] = *(const bf16x8_t*)&Am[r];
            al[mi] = *(const bf16x8_t*)&Al[r];
        }
#pragma unroll
        for (int ni = 0; ni < 4; ni++) {
            int rbb = (wc * 64 + ni * 16 + lm) * 32 + quad * 8;
            bf16x8_t bh = *(const bf16x8_t*)&Bh[rbb];
            bf16x8_t bm = *(const bf16x8_t*)&Bm[rbb];
            bf16x8_t bl = *(const bf16x8_t*)&Bl[rbb];
#pragma unroll
            for (int mi = 0; mi < 4; mi++)
                MFMA6(acc[mi][ni], ah[mi], am[mi], al[mi], bh, bm, bl);
        }
    }

#pragma unroll
    for (int mi = 0; mi < 4; mi++)
#pragma unroll
        for (int ni = 0; ni < 4; ni++) {
            int row = row0 + wr * 64 + mi * 16 + quad * 4;
            int col = col0 + wc * 64 + ni * 16 + lm;
#pragma unroll
            for (int r = 0; r < 4; r++)
                Cm[(size_t)(row + r) * NN + col] = acc[mi][ni][r] * scale;
        }
}

// ---------------------------------------------------------------------------
// Kernel 3: per (b,n): softmax stats for all 8 channels (no attn writeback),
// channel-summed probs -> top-16; writes ml, idx, cnt, countb; zeroes colsum.
// ---------------------------------------------------------------------------
__global__ __launch_bounds__(256) void softmax_topk(const float* __restrict__ attn,
                                                    float2* __restrict__ ml,
                                                    int* __restrict__ idx,
                                                    int* __restrict__ cnt,
                                                    int* __restrict__ countb,
                                                    float* __restrict__ colsum) {
    __shared__ float sum[NN];
    __shared__ float wsc[CC][8];
    __shared__ float tv[4];
    __shared__ int ti[4];
    __shared__ int fsel[MAXSEL];
    __shared__ int fcnt;
    const int bn = blockIdx.x, b = bn >> 10, n = bn & 1023;
    const int tid = threadIdx.x, lane = tid & 63, w = tid >> 6;
    const int m4 = tid * 4;

    if (tid < CC) colsum[(size_t)(b * CC + tid) * NN + n] = 0.f;

    float4 s4 = make_float4(0.f, 0.f, 0.f, 0.f);
#pragma unroll
    for (int c = 0; c < CC; c++) {
        float4 v = *(const float4*)(attn + (((size_t)(b * CC + c) * NN + n) * NN + m4));
        float mx = fmaxf(fmaxf(v.x, v.y), fmaxf(v.z, v.w));
#pragma unroll
        for (int off = 32; off; off >>= 1) mx = fmaxf(mx, __shfl_down(mx, off));
        if (lane == 0) wsc[c][w] = mx;
        __syncthreads();
        mx = fmaxf(fmaxf(wsc[c][0], wsc[c][1]), fmaxf(wsc[c][2], wsc[c][3]));
        v.x = expf(v.x - mx); v.y = expf(v.y - mx);
        v.z = expf(v.z - mx); v.w = expf(v.w - mx);
        float sm = v.x + v.y + v.z + v.w;
#pragma unroll
        for (int off = 32; off; off >>= 1) sm += __shfl_down(sm, off);
        if (lane == 0) wsc[c][4 + w] = sm;
        __syncthreads();
        float l = wsc[c][4] + wsc[c][5] + wsc[c][6] + wsc[c][7];
        if (tid == 0) ml[(size_t)(b * CC + c) * NN + n] = make_float2(mx, l);
        float inv = 1.0f / l;
        s4.x += v.x * inv; s4.y += v.y * inv; s4.z += v.z * inv; s4.w += v.w * inv;
    }
    *(float4*)&sum[m4] = s4;
    __syncthreads();

    // iterative top-16 (tie-break: lower index, matching jax.lax.top_k)
    for (int it = 0; it < KNBR; it++) {
        float bv = sum[m4]; int bi = m4;
#pragma unroll
        for (int j = 1; j < 4; j++) {
            float x = sum[m4 + j];
            if (x > bv) { bv = x; bi = m4 + j; }
        }
#pragma unroll
        for (int off = 32; off; off >>= 1) {
            float ov = __shfl_down(bv, off);
            int oi = __shfl_down(bi, off);
            if (ov > bv || (ov == bv && oi < bi)) { bv = ov; bi = oi; }
        }
        if (lane == 0) { tv[w] = bv; ti[w] = bi; }
        __syncthreads();
        if (tid == 0) {
            float cv = tv[0]; int ci = ti[0];
#pragma unroll
            for (int k = 1; k < 4; k++)
                if (tv[k] > cv || (tv[k] == cv && ti[k] < ci)) { cv = tv[k]; ci = ti[k]; }
            fsel[it] = ci;
            sum[ci] = -INFINITY;
        }
        __syncthreads();
    }
    if (tid == 0) {
        bool has = false;
        for (int t = 0; t < KNBR; t++)
            if (fsel[t] == n) has = true;
        int c = KNBR;
        if (!has) { fsel[KNBR] = n; c = KNBR + 1; }
        fcnt = c;
        cnt[bn] = c;
    }
    __syncthreads();
    if (tid < fcnt) {
        idx[bn * MAXSEL + tid] = fsel[tid];
        atomicAdd(&countb[b * NN + fsel[tid]], 1);
    }
}

// ---------------------------------------------------------------------------
// Kernel 4: per b: exclusive prefix scan of countb -> offb; init curs for
// the 8 z's of this b.
// ---------------------------------------------------------------------------
__global__ __launch_bounds__(256) void scan_offb(const int* __restrict__ countb,
                                                 int* __restrict__ offb,
                                                 int* __restrict__ curs) {
    __shared__ int wtot[4];
    const int b = blockIdx.x, tid = threadIdx.x, lane = tid & 63, w = tid >> 6;
    int c0 = countb[b * NN + tid * 4 + 0];
    int c1 = countb[b * NN + tid * 4 + 1];
    int c2 = countb[b * NN + tid * 4 + 2];
    int c3 = countb[b * NN + tid * 4 + 3];
    int tsum = c0 + c1 + c2 + c3;
    int incl = tsum;
#pragma unroll
    for (int off = 1; off < 64; off <<= 1) {
        int v = __shfl_up(incl, off);
        if (lane >= off) incl += v;
    }
    if (lane == 63) wtot[w] = incl;
    __syncthreads();
    int woff = 0;
    for (int i = 0; i < w; i++) woff += wtot[i];
    int base = woff + incl - tsum;
    int o0 = base, o1 = base + c0, o2 = base + c0 + c1, o3 = base + c0 + c1 + c2;
    offb[b * NN + tid * 4 + 0] = o0;
    offb[b * NN + tid * 4 + 1] = o1;
    offb[b * NN + tid * 4 + 2] = o2;
    offb[b * NN + tid * 4 + 3] = o3;
#pragma unroll
    for (int c = 0; c < CC; c++) {
        int z = b * CC + c;
        curs[z * NN + tid * 4 + 0] = o0;
        curs[z * NN + tid * 4 + 1] = o1;
        curs[z * NN + tid * 4 + 2] = o2;
        curs[z * NN + tid * 4 + 3] = o3;
    }
}

// ---------------------------------------------------------------------------
// Kernel 5 (merged rownorm + fill_csr): per (z,n) thread: recompute 17 masked
// probs from raw logits + (max,denom); row-normalize; accumulate colsum;
// append raw row-normalized values to CSR (colsum division deferred to
// out_sparse, so no dependency on complete colsum here).
// ---------------------------------------------------------------------------
__global__ __launch_bounds__(256) void rownorm_fill(const float* __restrict__ attn,
                                                    const float2* __restrict__ ml,
                                                    const int* __restrict__ idx,
                                                    const int* __restrict__ cnt,
                                                    int* __restrict__ curs,
                                                    float* __restrict__ nr,
                                                    float* __restrict__ colsum,
                                                    int* __restrict__ eidx,
                                                    float* __restrict__ eval) {
    const int t = blockIdx.x * 256 + threadIdx.x;  // z*N + n
    const int z = t >> 10, n = t & 1023;
    const int b = z >> 3;
    const int bn = b * NN + n;
    const int c_ = cnt[bn];
    const float* arow = attn + (size_t)t * NN;
    const float2 MM = ml[t];
    const float invl = 1.0f / MM.y;
    const size_t zb = (size_t)z * ZCAP;
    float a[MAXSEL];
    int kk[MAXSEL];
    float s = 0.f;
#pragma unroll
    for (int j = 0; j < MAXSEL; j++) {
        if (j < c_) {
            kk[j] = idx[bn * MAXSEL + j];
            float p = expf(arow[kk[j]] - MM.x) * invl;
            a[j] = p; s += p;
        }
    }
    const float inv = 1.f / (s + 1e-6f);
#pragma unroll
    for (int j = 0; j < MAXSEL; j++) {
        if (j < c_) {
            float v = a[j] * inv;
            nr[(size_t)t * MAXSEL + j] = v;
            atomicAdd(&colsum[(size_t)z * NN + kk[j]], v);
            int p = atomicAdd(&curs[z * NN + kk[j]], 1);
            eidx[zb + p] = n;
            eval[zb + p] = v;
        }
    }
}

// ---------------------------------------------------------------------------
// Kernel 6: out[z][n][:] = sum_j w_j/(colsum_j+eps) * sparse_col(k_j).
// Block per (z,n). 17 groups of 15 threads; group j owns column k_j's
// contiguous CSR slice — no prefix scan, no search.
// ---------------------------------------------------------------------------
__global__ __launch_bounds__(256) void out_sparse(const float* __restrict__ nr,
                                                  const int* __restrict__ idx,
                                                  const int* __restrict__ cnt,
                                                  const int* __restrict__ offb,
                                                  const int* __restrict__ countb,
                                                  const float* __restrict__ colsum,
                                                  const int* __restrict__ eidx,
                                                  const float* __restrict__ eval,
                                                  float* __restrict__ out) {
    __shared__ float row[NN];
    __shared__ float gscale[MAXSEL];
    __shared__ int goff[MAXSEL];
    __shared__ int glen[MAXSEL];
    const int t = blockIdx.x;  // z*N + n
    const int z = t >> 10;
    const int b = z >> 3;
    const int bn = b * NN + (t & 1023);
    const int tid = threadIdx.x;
    const size_t zb = (size_t)z * ZCAP;

    ((float4*)row)[tid] = make_float4(0.f, 0.f, 0.f, 0.f);
    const int c_ = cnt[bn];
    if (tid < MAXSEL) {
        float sc = 0.f;
        int off = 0, len = 0;
        if (tid < c_) {
            int k = idx[bn * MAXSEL + tid];
            float wgt = nr[(size_t)t * MAXSEL + tid];
            sc = wgt / (colsum[(size_t)z * NN + k] + 1e-6f);
            off = offb[b * NN + k];
            len = countb[b * NN + k];
        }
        gscale[tid] = sc; goff[tid] = off; glen[tid] = len;
    }
    __syncthreads();
    const int j = tid / 15;       // 17 groups of 15 (tid 255 idle)
    const int lg = tid - j * 15;
    if (j < MAXSEL) {
        const float sc = gscale[j];
        const int off = goff[j], len = glen[j];
        for (int i = lg; i < len; i += 15) {
            int m = eidx[zb + off + i];
            float v = eval[zb + off + i];
            atomicAdd(&row[m], sc * v);
        }
    }
    __syncthreads();
    *(float4*)(out + (size_t)t * NN + tid * 4) = ((float4*)row)[tid];
}

// ---------------------------------------------------------------------------
extern "C" void kernel_launch(void* const* d_in, const int* in_sizes, int n_in,
                              void* d_out, int out_size, void* d_ws, size_t ws_size,
                              hipStream_t stream) {
    const float* x = (const float*)d_in[0];    // [4,1024,256]
    const float* W = (const float*)d_in[1];    // [256,4096]
    float* out = (float*)d_out;                // [4,8,1024,1024]
    char* ws = (char*)d_ws;

    // attn (raw logits*scale) lives in d_out; dead before out_sparse writes.
    float* attn = (float*)d_out;

    // workspace layout (bytes)
    __bf16* qh   = (__bf16*)(ws);
    __bf16* qm   = (__bf16*)(ws + 16777216ull);
    __bf16* ql   = (__bf16*)(ws + 33554432ull);
    __bf16* kh   = (__bf16*)(ws + 50331648ull);
    __bf16* km   = (__bf16*)(ws + 67108864ull);
    __bf16* kl   = (__bf16*)(ws + 83886080ull);
    __bf16* xh   = (__bf16*)(ws + 100663296ull);
    __bf16* xm   = (__bf16*)(ws + 102760448ull);
    __bf16* xl   = (__bf16*)(ws + 104857600ull);
    __bf16* wth  = (__bf16*)(ws + 106954752ull);
    __bf16* wtm  = (__bf16*)(ws + 109051904ull);
    __bf16* wtl  = (__bf16*)(ws + 111149056ull);
    int*    idx  = (int*)   (ws + 113246208ull);   // 278,528
    int*    cnt  = (int*)   (ws + 113524736ull);   // 16,384
    float*  nr   = (float*) (ws + 113541120ull);   // 2,228,224
    float*  colsum = (float*)(ws + 115769344ull);  // 131,072
    float2* ml   = (float2*)(ws + 115900416ull);   // 262,144
    int*    countb = (int*) (ws + 116162560ull);   // 16,384
    int*    offb = (int*)   (ws + 116178944ull);   // 16,384
    int*    curs = (int*)   (ws + 116195328ull);   // 131,072
    int*    eidx = (int*)   (ws + 116326400ull);   // 2,228,224
    float*  eval = (float*) (ws + 118554624ull);   // 2,228,224

    split_all<<<1280, 256, 0, stream>>>(x, W, xh, xm, xl, wth, wtm, wtl, countb);
    gemm_xw_mfma<<<dim3(32, 32), 256, 0, stream>>>(xh, xm, xl, wth, wtm, wtl,
                                                   qh, qm, ql, kh, km, kl);
    gemm_qkt_mfma<<<2048, 256, 0, stream>>>(qh, qm, ql, kh, km, kl, attn);
    softmax_topk<<<4096, 256, 0, stream>>>(attn, ml, idx, cnt, countb, colsum);
    scan_offb<<<4, 256, 0, stream>>>(countb, offb, curs);
    rownorm_fill<<<128, 256, 0, stream>>>(attn, ml, idx, cnt, curs, nr, colsum,
                                          eidx, eval);
    out_sparse<<<32768, 256, 0, stream>>>(nr, idx, cnt, offb, countb, colsum,
                                          eidx, eval, out);
}